// Round 8
// baseline (2670.813 us; speedup 1.0000x reference)
//
#include <hip/hip_runtime.h>

#define N_NODES 100000
#define N_EDGES 1000000
#define DIM 64
#define N_GRAPHS 1024
#define OUT_DIM 16
#define NLAYERS 4

#define BN 64        // nodes per block in layer kernel
#define NB 1563      // ceil(N_NODES/BN)
#define BLOCK 512    // 8 waves
#define NWAVES 8
#define SA 65        // agg_s row stride: 65%32==1 -> 2-way alias, free
#define SX 68        // x_s row stride: mult of 4 for float4 LDS ops
#define SENTINEL (BN << 17)  // dump row BN, src 0

#define SCAN_NB 98   // ceil((N_NODES+1)/1024)

__device__ __forceinline__ float b2f(unsigned short u) {
    union { unsigned int i; float f; } c;
    c.i = ((unsigned int)u) << 16;
    return c.f;
}
__device__ __forceinline__ unsigned short f2b(float f) {  // RNE
    union { float f; unsigned int i; } c;
    c.f = f;
    return (unsigned short)((c.i + 0x7FFFu + ((c.i >> 16) & 1u)) >> 16);
}

// ---------------- CSR build ----------------
__global__ void count_kernel(const int* __restrict__ dst, int* __restrict__ counts) {
    int e = blockIdx.x * blockDim.x + threadIdx.x;
    if (e < N_EDGES) atomicAdd(&counts[dst[e]], 1);  // int atomic: native
}

__global__ __launch_bounds__(1024) void scan_reduce_kernel(const int* __restrict__ counts,
                                                           int* __restrict__ bsums) {
    int i = blockIdx.x * 1024 + threadIdx.x;
    int v = (i < N_NODES) ? counts[i] : 0;
    __shared__ int ws_[16];
    for (int off = 32; off > 0; off >>= 1) v += __shfl_down(v, off, 64);
    if ((threadIdx.x & 63) == 0) ws_[threadIdx.x >> 6] = v;
    __syncthreads();
    if (threadIdx.x < 16) {
        int s = ws_[threadIdx.x];
        for (int off = 8; off > 0; off >>= 1) s += __shfl_down(s, off, 16);
        if (threadIdx.x == 0) bsums[blockIdx.x] = s;
    }
}

__global__ __launch_bounds__(128) void scan_sums_kernel(int* __restrict__ bsums) {
    __shared__ int t[128];
    int i = threadIdx.x;
    t[i] = (i < SCAN_NB) ? bsums[i] : 0;
    __syncthreads();
    for (int off = 1; off < 128; off <<= 1) {
        int v = (i >= off) ? t[i - off] : 0;
        __syncthreads();
        t[i] += v;
        __syncthreads();
    }
    if (i < SCAN_NB) bsums[i] = (i > 0) ? t[i - 1] : 0;  // exclusive
}

__global__ __launch_bounds__(1024) void scan_apply_kernel(const int* __restrict__ counts,
                                                          const int* __restrict__ bsums,
                                                          int* __restrict__ row_ptr,
                                                          int* __restrict__ cursor) {
    int i = blockIdx.x * 1024 + threadIdx.x;
    int v = (i < N_NODES) ? counts[i] : 0;
    int lane = threadIdx.x & 63, w = threadIdx.x >> 6;
    int inc = v;
    for (int off = 1; off < 64; off <<= 1) {
        int u = __shfl_up(inc, off, 64);
        if (lane >= off) inc += u;
    }
    __shared__ int wsum[16];
    if (lane == 63) wsum[w] = inc;
    __syncthreads();
    if (threadIdx.x < 16) {
        int s = wsum[threadIdx.x];
        for (int off = 1; off < 16; off <<= 1) {
            int u = __shfl_up(s, off, 16);
            if (threadIdx.x >= off) s += u;
        }
        wsum[threadIdx.x] = s;
    }
    __syncthreads();
    int excl = inc - v + (w > 0 ? wsum[w - 1] : 0) + bsums[blockIdx.x];
    if (i <= N_NODES) row_ptr[i] = excl;
    if (i < N_NODES) cursor[i] = excl;
}

__global__ void scatter_kernel(const int* __restrict__ src, const int* __restrict__ dst,
                               int* __restrict__ cursor, int* __restrict__ edges) {
    int e = blockIdx.x * blockDim.x + threadIdx.x;
    if (e < N_EDGES) {
        int d = dst[e];
        int pos = atomicAdd(&cursor[d], 1);  // int atomic: native
        edges[pos] = ((d & 63) << 17) | src[e];  // 6b dst_local | 17b src
    }
}

// ---------------- x -> bf16 convert ----------------
__global__ __launch_bounds__(256) void tobf_kernel(const float4* __restrict__ in,
                                                   ushort4* __restrict__ out) {
    const int n4 = N_NODES * (DIM / 4);
    for (int i = blockIdx.x * blockDim.x + threadIdx.x; i < n4; i += gridDim.x * blockDim.x) {
        float4 v = in[i];
        ushort4 b;
        b.x = f2b(v.x); b.y = f2b(v.y); b.z = f2b(v.z); b.w = f2b(v.w);
        out[i] = b;
    }
}

// ---------------- fused GraphConv layer ----------------
// Phase A (edge-stream, chain-broken): per wave, contiguous edge chunk.
//   Per 64-edge batch: 1 coalesced payload load -> LDS slab; then two 8-deep
//   pipelined chunks (8 independent slab reads, 8 independent 512B row-gathers
//   in flight), accumulate via ds_add_f32 (unsafeAtomicAdd on LDS — native,
//   fire-and-forget; plain atomicAdd(float) is a CAS loop = R2's 240cyc/op).
//   Sentinel padding (dump row) keeps the loop branch-free.
// Phase B: wave w computes dims [8w,8w+8) for all 64 nodes; weights wave-uniform.
__global__ __launch_bounds__(BLOCK) void layer_kernel(
    const float* __restrict__ hin, const ushort4* __restrict__ hbf_in,
    float* __restrict__ hout, ushort4* __restrict__ hbf_out,
    const float* __restrict__ Wrel, const float* __restrict__ brel,
    const float* __restrict__ Wroot,
    const int* __restrict__ row_ptr, const int* __restrict__ edges) {
    __shared__ float agg_s[(BN + 1) * SA];   // +1 dump row for sentinel edges
    __shared__ float x_s[BN * SX];
    __shared__ int idx_s[NWAVES * 64];
    const int tid = threadIdx.x;
    const int lane = tid & 63;
    const int wave = __builtin_amdgcn_readfirstlane(tid >> 6);
    const int grp = lane >> 4;   // 4 groups of 16 lanes
    const int gl = lane & 15;    // ushort4 slot within row (4 dims)
    const int node0 = blockIdx.x * BN;
    const int nvalid = min(BN, N_NODES - node0);

    for (int i = tid; i < (BN + 1) * SA; i += BLOCK) agg_s[i] = 0.f;
    // stage own x rows (coalesced float4)
    for (int i = tid; i < nvalid * (DIM / 4); i += BLOCK) {
        int nl = i >> 4;
        int c = i & 15;
        float4 v = reinterpret_cast<const float4*>(hin)[(size_t)(node0 + nl) * (DIM / 4) + c];
        reinterpret_cast<float4*>(x_s)[nl * (SX / 4) + c] = v;
    }
    __syncthreads();  // agg_s zeroed before any ds_add

    // Phase A
    const int ebeg = row_ptr[node0];
    const int eend = row_ptr[node0 + nvalid];
    const int total = eend - ebeg;
    const int chunk = (total + NWAVES - 1) / NWAVES;
    int wbeg = ebeg + wave * chunk;
    int wend = min(wbeg + chunk, eend);
    int* slab = &idx_s[wave * 64];

    for (int b = wbeg; b < wend; b += 64) {
        int n = wend - b;
        if (n > 64) n = 64;
        slab[lane] = (lane < n) ? edges[b + lane] : SENTINEL;  // same-wave: no barrier
        // group g owns edges [g*16 + c*8, +8) of this batch
#pragma unroll
        for (int c = 0; c < 2; ++c) {
            int pj[8];
#pragma unroll
            for (int it = 0; it < 8; ++it) pj[it] = slab[grp * 16 + c * 8 + it];
            ushort4 uj[8];
#pragma unroll
            for (int it = 0; it < 8; ++it)
                uj[it] = hbf_in[(size_t)(pj[it] & 0x1FFFF) * 16 + gl];  // 8 x 512B in flight
#pragma unroll
            for (int it = 0; it < 8; ++it) {
                float* base = &agg_s[(pj[it] >> 17) * SA + gl * 4];
                unsafeAtomicAdd(base + 0, b2f(uj[it].x));
                unsafeAtomicAdd(base + 1, b2f(uj[it].y));
                unsafeAtomicAdd(base + 2, b2f(uj[it].z));
                unsafeAtomicAdd(base + 3, b2f(uj[it].w));
            }
        }
    }
    __syncthreads();

    // Phase B: node = lane, dim-octet = wave
    const int d0 = wave * 8;
    float out[8];
#pragma unroll
    for (int j = 0; j < 8; ++j) out[j] = brel[d0 + j];  // uniform -> scalar
    const float* ar = &agg_s[lane * SA];
    const float* xr = &x_s[lane * SX];
    for (int k = 0; k < DIM; ++k) {
        float a = ar[k];
        float xv = xr[k];
        const float* wr = &Wrel[k * DIM + d0];   // wave-uniform -> s_load
        const float* wo = &Wroot[k * DIM + d0];
#pragma unroll
        for (int j = 0; j < 8; ++j)
            out[j] = fmaf(a, wr[j], fmaf(xv, wo[j], out[j]));
    }

    __syncthreads();  // all waves done reading x_s
    if (lane < nvalid) {
#pragma unroll
        for (int j = 0; j < 8; ++j) x_s[lane * SX + d0 + j] = fmaxf(out[j], 0.f);
    }
    __syncthreads();

    // coalesced stores: fp32 h + bf16 gather copy
    for (int i = tid; i < nvalid * (DIM / 4); i += BLOCK) {
        int nl = i >> 4;
        int c = i & 15;
        float4 v = reinterpret_cast<const float4*>(x_s)[nl * (SX / 4) + c];
        reinterpret_cast<float4*>(hout)[(size_t)(node0 + nl) * (DIM / 4) + c] = v;
        ushort4 b;
        b.x = f2b(v.x); b.y = f2b(v.y); b.z = f2b(v.z); b.w = f2b(v.w);
        hbf_out[(size_t)(node0 + nl) * 16 + c] = b;
    }
}

// ---------------- global add pool ----------------
__global__ __launch_bounds__(256) void pool_kernel(const float* __restrict__ h,
                                                   const int* __restrict__ batch,
                                                   float* __restrict__ g) {
    int gtid = blockIdx.x * blockDim.x + threadIdx.x;
    int w = gtid >> 6;
    int lane = gtid & 63;
    const int NW = 1024;
    const int CH = (N_NODES + NW - 1) / NW;  // 98
    int nb = w * CH;
    int ne = min(nb + CH, N_NODES);
    if (nb >= ne) return;
    float acc = 0.f;
    int cur = batch[nb];
    for (int n = nb; n < ne; ++n) {
        int b = batch[n];  // wave-uniform broadcast
        if (b != cur) {
            unsafeAtomicAdd(&g[(size_t)cur * DIM + lane], acc);  // native f32 atomic
            acc = 0.f;
            cur = b;
        }
        acc += h[(size_t)n * DIM + lane];
    }
    unsafeAtomicAdd(&g[(size_t)cur * DIM + lane], acc);
}

// ---------------- classifier head ----------------
__global__ __launch_bounds__(256) void head_kernel(
    const float* __restrict__ g, const float* __restrict__ W1, const float* __restrict__ b1,
    const float* __restrict__ W2, const float* __restrict__ b2, float* __restrict__ y) {
    int gid = blockIdx.x * blockDim.x + threadIdx.x;
    if (gid >= N_GRAPHS) return;
    float t[DIM];
#pragma unroll
    for (int d = 0; d < DIM; ++d) t[d] = b1[d];
    const float4* gp = reinterpret_cast<const float4*>(g + (size_t)gid * DIM);
    for (int kk = 0; kk < DIM / 4; ++kk) {
        float4 gv = gp[kk];
        float ga[4] = {gv.x, gv.y, gv.z, gv.w};
#pragma unroll
        for (int c = 0; c < 4; ++c) {
            int k = 4 * kk + c;
            float v = ga[c];
#pragma unroll
            for (int d = 0; d < DIM; ++d) t[d] = fmaf(v, W1[k * DIM + d], t[d]);
        }
    }
#pragma unroll
    for (int d = 0; d < DIM; ++d) t[d] = fmaxf(t[d], 0.f);
    for (int o = 0; o < OUT_DIM; ++o) {
        float acc = b2[o];
#pragma unroll
        for (int d = 0; d < DIM; ++d) acc = fmaf(t[d], W2[d * OUT_DIM + o], acc);
        y[(size_t)gid * OUT_DIM + o] = acc;
    }
}

extern "C" void kernel_launch(void* const* d_in, const int* in_sizes, int n_in,
                              void* d_out, int out_size, void* d_ws, size_t ws_size,
                              hipStream_t stream) {
    const float* x     = (const float*)d_in[0];
    const int*   eidx  = (const int*)d_in[1];
    const int*   batch = (const int*)d_in[2];
    const float* Wrel  = (const float*)d_in[3];
    const float* brel  = (const float*)d_in[4];
    const float* Wroot = (const float*)d_in[5];
    const float* W1    = (const float*)d_in[6];
    const float* b1    = (const float*)d_in[7];
    const float* W2    = (const float*)d_in[8];
    const float* b2    = (const float*)d_in[9];
    float* y = (float*)d_out;

    char* ws = (char*)d_ws;
    const size_t HBYTES  = (size_t)N_NODES * DIM * sizeof(float);          // 25.6 MB
    const size_t BFBYTES = (size_t)N_NODES * DIM * sizeof(unsigned short); // 12.8 MB
    size_t off = 0;
    float* hA = (float*)(ws + off); off += HBYTES;
    float* hB = (float*)(ws + off); off += HBYTES;
    ushort4* bf0 = (ushort4*)(ws + off); off += BFBYTES;
    ushort4* bf1 = (ushort4*)(ws + off); off += BFBYTES;
    int* row_ptr = (int*)(ws + off); off += (((size_t)(N_NODES + 1) * 4 + 255) / 256) * 256;
    int* cursor  = (int*)(ws + off); off += (((size_t)N_NODES * 4 + 255) / 256) * 256;
    int* edges   = (int*)(ws + off); off += (size_t)N_EDGES * 4;
    float* g     = (float*)(ws + off); off += (size_t)N_GRAPHS * DIM * 4;
    int* bsums   = (int*)(ws + off); off += 128 * 4;

    const int* src = eidx;
    const int* dst = eidx + N_EDGES;

    // CSR build (once, reused across 4 layers)
    hipMemsetAsync(row_ptr, 0, (size_t)N_NODES * sizeof(int), stream);
    count_kernel<<<(N_EDGES + 255) / 256, 256, 0, stream>>>(dst, row_ptr);
    scan_reduce_kernel<<<SCAN_NB, 1024, 0, stream>>>(row_ptr, bsums);
    scan_sums_kernel<<<1, 128, 0, stream>>>(bsums);
    scan_apply_kernel<<<SCAN_NB, 1024, 0, stream>>>(row_ptr, bsums, row_ptr, cursor);
    scatter_kernel<<<(N_EDGES + 255) / 256, 256, 0, stream>>>(src, dst, cursor, edges);

    // bf16 copy of x for the first layer's gather
    tobf_kernel<<<1024, 256, 0, stream>>>((const float4*)x, bf0);

    // 4 GraphConv layers, ping-pong (fp32 + bf16 streams)
    const float* hin = x;
    const ushort4* bin = bf0;
    float* fbufs[2] = {hA, hB};
    ushort4* bbufs[2] = {bf1, bf0};
    for (int l = 0; l < NLAYERS; ++l) {
        float* hout = fbufs[l & 1];
        ushort4* bout = bbufs[l & 1];
        layer_kernel<<<NB, BLOCK, 0, stream>>>(hin, bin, hout, bout,
                                               Wrel + (size_t)l * DIM * DIM,
                                               brel + (size_t)l * DIM,
                                               Wroot + (size_t)l * DIM * DIM,
                                               row_ptr, edges);
        hin = hout;
        bin = bout;
    }

    // global add pool
    hipMemsetAsync(g, 0, (size_t)N_GRAPHS * DIM * sizeof(float), stream);
    pool_kernel<<<256, 256, 0, stream>>>(hin, batch, g);

    // head
    head_kernel<<<(N_GRAPHS + 255) / 256, 256, 0, stream>>>(g, W1, b1, W2, b2, y);
}

// Round 9
// 543.516 us; speedup vs baseline: 4.9140x; 4.9140x over previous
//
#include <hip/hip_runtime.h>

#define N_NODES 100000
#define N_EDGES 1000000
#define DIM 64
#define N_GRAPHS 1024
#define OUT_DIM 16
#define NLAYERS 4

#define BN 64        // nodes per block in layer kernel
#define NB 1563      // ceil(N_NODES/BN)
#define BLOCK 512    // 8 waves
#define NWAVES 8
#define RPW 8        // dst rows owned per wave -> no atomics
#define SA 65        // agg_s row stride: 65%32==1 -> 2-way alias, free
#define SX 68        // x_s row stride: mult of 4 for float4 LDS ops

#define SCAN_NB 98   // ceil((N_NODES+1)/1024)

typedef unsigned short ushort8_t __attribute__((ext_vector_type(8)));

__device__ __forceinline__ float b2f(unsigned short u) {
    union { unsigned int i; float f; } c;
    c.i = ((unsigned int)u) << 16;
    return c.f;
}
__device__ __forceinline__ unsigned short f2b(float f) {  // RNE
    union { float f; unsigned int i; } c;
    c.f = f;
    return (unsigned short)((c.i + 0x7FFFu + ((c.i >> 16) & 1u)) >> 16);
}

// ---------------- CSR build ----------------
__global__ void count_kernel(const int* __restrict__ dst, int* __restrict__ counts) {
    int e = blockIdx.x * blockDim.x + threadIdx.x;
    if (e < N_EDGES) atomicAdd(&counts[dst[e]], 1);  // int atomic: native
}

__global__ __launch_bounds__(1024) void scan_reduce_kernel(const int* __restrict__ counts,
                                                           int* __restrict__ bsums) {
    int i = blockIdx.x * 1024 + threadIdx.x;
    int v = (i < N_NODES) ? counts[i] : 0;
    __shared__ int ws_[16];
    for (int off = 32; off > 0; off >>= 1) v += __shfl_down(v, off, 64);
    if ((threadIdx.x & 63) == 0) ws_[threadIdx.x >> 6] = v;
    __syncthreads();
    if (threadIdx.x < 16) {
        int s = ws_[threadIdx.x];
        for (int off = 8; off > 0; off >>= 1) s += __shfl_down(s, off, 16);
        if (threadIdx.x == 0) bsums[blockIdx.x] = s;
    }
}

__global__ __launch_bounds__(128) void scan_sums_kernel(int* __restrict__ bsums) {
    __shared__ int t[128];
    int i = threadIdx.x;
    t[i] = (i < SCAN_NB) ? bsums[i] : 0;
    __syncthreads();
    for (int off = 1; off < 128; off <<= 1) {
        int v = (i >= off) ? t[i - off] : 0;
        __syncthreads();
        t[i] += v;
        __syncthreads();
    }
    if (i < SCAN_NB) bsums[i] = (i > 0) ? t[i - 1] : 0;  // exclusive
}

__global__ __launch_bounds__(1024) void scan_apply_kernel(const int* __restrict__ counts,
                                                          const int* __restrict__ bsums,
                                                          int* __restrict__ row_ptr,
                                                          int* __restrict__ cursor) {
    int i = blockIdx.x * 1024 + threadIdx.x;
    int v = (i < N_NODES) ? counts[i] : 0;
    int lane = threadIdx.x & 63, w = threadIdx.x >> 6;
    int inc = v;
    for (int off = 1; off < 64; off <<= 1) {
        int u = __shfl_up(inc, off, 64);
        if (lane >= off) inc += u;
    }
    __shared__ int wsum[16];
    if (lane == 63) wsum[w] = inc;
    __syncthreads();
    if (threadIdx.x < 16) {
        int s = wsum[threadIdx.x];
        for (int off = 1; off < 16; off <<= 1) {
            int u = __shfl_up(s, off, 16);
            if (threadIdx.x >= off) s += u;
        }
        wsum[threadIdx.x] = s;
    }
    __syncthreads();
    int excl = inc - v + (w > 0 ? wsum[w - 1] : 0) + bsums[blockIdx.x];
    if (i <= N_NODES) row_ptr[i] = excl;
    if (i < N_NODES) cursor[i] = excl;
}

__global__ void scatter_kernel(const int* __restrict__ src, const int* __restrict__ dst,
                               int* __restrict__ cursor, int* __restrict__ edges) {
    int e = blockIdx.x * blockDim.x + threadIdx.x;
    if (e < N_EDGES) {
        int pos = atomicAdd(&cursor[dst[e]], 1);  // int atomic: native
        edges[pos] = src[e];
    }
}

// ---------------- x -> bf16 convert ----------------
__global__ __launch_bounds__(256) void tobf_kernel(const float4* __restrict__ in,
                                                   ushort4* __restrict__ out) {
    const int n4 = N_NODES * (DIM / 4);
    for (int i = blockIdx.x * blockDim.x + threadIdx.x; i < n4; i += gridDim.x * blockDim.x) {
        float4 v = in[i];
        ushort4 b;
        b.x = f2b(v.x); b.y = f2b(v.y); b.z = f2b(v.z); b.w = f2b(v.w);
        out[i] = b;
    }
}

// ---------------- fused GraphConv layer ----------------
// Phase A: wave w owns dst rows [8w,8w+8), register accumulation (no atomics:
//          HIP atomicAdd(float) is a CAS loop; LDS unsafeAtomicAdd is worse).
//          Octet-gather: 8 lanes per src row, ushort8 (16B dwordx4)/lane ->
//          one VMEM instruction gathers 8 FULL bf16 rows (8 edges). 16-edge
//          unroll keeps 2 gathers in flight; 3-level shfl_xor cross-group reduce.
// Phase B: wave w computes dims [8w,8w+8) for all 64 nodes; weights wave-uniform.
__global__ __launch_bounds__(BLOCK) void layer_kernel(
    const float* __restrict__ hin, const ushort8_t* __restrict__ hbf_in,
    float* __restrict__ hout, ushort4* __restrict__ hbf_out,
    const float* __restrict__ Wrel, const float* __restrict__ brel,
    const float* __restrict__ Wroot,
    const int* __restrict__ row_ptr, const int* __restrict__ edges) {
    __shared__ float agg_s[BN * SA];
    __shared__ float x_s[BN * SX];
    const int tid = threadIdx.x;
    const int lane = tid & 63;
    const int wave = __builtin_amdgcn_readfirstlane(tid >> 6);
    const int grp8 = lane >> 3;  // which of 8 concurrent edges
    const int gl8 = lane & 7;    // ushort8 slot within row (8 dims)
    const int node0 = blockIdx.x * BN;
    const int nvalid = min(BN, N_NODES - node0);

    // stage own x rows (coalesced float4)
    for (int i = tid; i < nvalid * (DIM / 4); i += BLOCK) {
        int nl = i >> 4;
        int c = i & 15;
        float4 v = reinterpret_cast<const float4*>(hin)[(size_t)(node0 + nl) * (DIM / 4) + c];
        reinterpret_cast<float4*>(x_s)[nl * (SX / 4) + c] = v;
    }

    // Phase A
    const int r0 = node0 + wave * RPW;
#pragma unroll
    for (int r8 = 0; r8 < RPW; ++r8) {
        int rg = r0 + r8;
        if (rg >= N_NODES) break;
        int e = row_ptr[rg];            // wave-uniform -> scalar
        const int ee = row_ptr[rg + 1];
        float a[8];
#pragma unroll
        for (int j = 0; j < 8; ++j) a[j] = 0.f;
        for (; e + 16 <= ee; e += 16) {   // 16 edges, 2 gather instrs in flight
            int s0 = edges[e + grp8];
            int s1 = edges[e + 8 + grp8];
            ushort8_t u0 = hbf_in[(size_t)s0 * 8 + gl8];   // 8 rows / instruction
            ushort8_t u1 = hbf_in[(size_t)s1 * 8 + gl8];
#pragma unroll
            for (int j = 0; j < 8; ++j) a[j] += b2f(u0[j]) + b2f(u1[j]);
        }
        for (; e + 8 <= ee; e += 8) {
            int s = edges[e + grp8];
            ushort8_t u = hbf_in[(size_t)s * 8 + gl8];
#pragma unroll
            for (int j = 0; j < 8; ++j) a[j] += b2f(u[j]);
        }
        int rem = ee - e;
        if (grp8 < rem) {
            int s = edges[e + grp8];
            ushort8_t u = hbf_in[(size_t)s * 8 + gl8];
#pragma unroll
            for (int j = 0; j < 8; ++j) a[j] += b2f(u[j]);
        }
        // reduce across the 8 groups (lanes differing in bits 3,4,5)
#pragma unroll
        for (int j = 0; j < 8; ++j) {
            a[j] += __shfl_xor(a[j], 8, 64);
            a[j] += __shfl_xor(a[j], 16, 64);
            a[j] += __shfl_xor(a[j], 32, 64);
        }
        if (grp8 == 0) {  // lanes 0..7 hold dims [8*gl8, +8)
#pragma unroll
            for (int j = 0; j < 8; ++j)
                agg_s[(wave * RPW + r8) * SA + gl8 * 8 + j] = a[j];
        }
    }
    __syncthreads();

    // Phase B: node = lane, dim-octet = wave
    const int d0 = wave * 8;
    float out[8];
#pragma unroll
    for (int j = 0; j < 8; ++j) out[j] = brel[d0 + j];  // uniform -> scalar
    const float* ar = &agg_s[lane * SA];
    const float* xr = &x_s[lane * SX];
    for (int k = 0; k < DIM; ++k) {
        float a = ar[k];
        float xv = xr[k];
        const float* wr = &Wrel[k * DIM + d0];   // wave-uniform -> s_load
        const float* wo = &Wroot[k * DIM + d0];
#pragma unroll
        for (int j = 0; j < 8; ++j)
            out[j] = fmaf(a, wr[j], fmaf(xv, wo[j], out[j]));
    }

    __syncthreads();  // all waves done reading x_s
    if (lane < nvalid) {
#pragma unroll
        for (int j = 0; j < 8; ++j) x_s[lane * SX + d0 + j] = fmaxf(out[j], 0.f);
    }
    __syncthreads();

    // coalesced stores: fp32 h + bf16 gather copy
    for (int i = tid; i < nvalid * (DIM / 4); i += BLOCK) {
        int nl = i >> 4;
        int c = i & 15;
        float4 v = reinterpret_cast<const float4*>(x_s)[nl * (SX / 4) + c];
        reinterpret_cast<float4*>(hout)[(size_t)(node0 + nl) * (DIM / 4) + c] = v;
        ushort4 b;
        b.x = f2b(v.x); b.y = f2b(v.y); b.z = f2b(v.z); b.w = f2b(v.w);
        hbf_out[(size_t)(node0 + nl) * 16 + c] = b;
    }
}

// ---------------- global add pool ----------------
__global__ __launch_bounds__(256) void pool_kernel(const float* __restrict__ h,
                                                   const int* __restrict__ batch,
                                                   float* __restrict__ g) {
    int gtid = blockIdx.x * blockDim.x + threadIdx.x;
    int w = gtid >> 6;
    int lane = gtid & 63;
    const int NW = 1024;
    const int CH = (N_NODES + NW - 1) / NW;  // 98
    int nb = w * CH;
    int ne = min(nb + CH, N_NODES);
    if (nb >= ne) return;
    float acc = 0.f;
    int cur = batch[nb];
    for (int n = nb; n < ne; ++n) {
        int b = batch[n];  // wave-uniform broadcast
        if (b != cur) {
            unsafeAtomicAdd(&g[(size_t)cur * DIM + lane], acc);  // native f32 atomic
            acc = 0.f;
            cur = b;
        }
        acc += h[(size_t)n * DIM + lane];
    }
    unsafeAtomicAdd(&g[(size_t)cur * DIM + lane], acc);
}

// ---------------- classifier head ----------------
__global__ __launch_bounds__(256) void head_kernel(
    const float* __restrict__ g, const float* __restrict__ W1, const float* __restrict__ b1,
    const float* __restrict__ W2, const float* __restrict__ b2, float* __restrict__ y) {
    int gid = blockIdx.x * blockDim.x + threadIdx.x;
    if (gid >= N_GRAPHS) return;
    float t[DIM];
#pragma unroll
    for (int d = 0; d < DIM; ++d) t[d] = b1[d];
    const float4* gp = reinterpret_cast<const float4*>(g + (size_t)gid * DIM);
    for (int kk = 0; kk < DIM / 4; ++kk) {
        float4 gv = gp[kk];
        float ga[4] = {gv.x, gv.y, gv.z, gv.w};
#pragma unroll
        for (int c = 0; c < 4; ++c) {
            int k = 4 * kk + c;
            float v = ga[c];
#pragma unroll
            for (int d = 0; d < DIM; ++d) t[d] = fmaf(v, W1[k * DIM + d], t[d]);
        }
    }
#pragma unroll
    for (int d = 0; d < DIM; ++d) t[d] = fmaxf(t[d], 0.f);
    for (int o = 0; o < OUT_DIM; ++o) {
        float acc = b2[o];
#pragma unroll
        for (int d = 0; d < DIM; ++d) acc = fmaf(t[d], W2[d * OUT_DIM + o], acc);
        y[(size_t)gid * OUT_DIM + o] = acc;
    }
}

extern "C" void kernel_launch(void* const* d_in, const int* in_sizes, int n_in,
                              void* d_out, int out_size, void* d_ws, size_t ws_size,
                              hipStream_t stream) {
    const float* x     = (const float*)d_in[0];
    const int*   eidx  = (const int*)d_in[1];
    const int*   batch = (const int*)d_in[2];
    const float* Wrel  = (const float*)d_in[3];
    const float* brel  = (const float*)d_in[4];
    const float* Wroot = (const float*)d_in[5];
    const float* W1    = (const float*)d_in[6];
    const float* b1    = (const float*)d_in[7];
    const float* W2    = (const float*)d_in[8];
    const float* b2    = (const float*)d_in[9];
    float* y = (float*)d_out;

    char* ws = (char*)d_ws;
    const size_t HBYTES  = (size_t)N_NODES * DIM * sizeof(float);          // 25.6 MB
    const size_t BFBYTES = (size_t)N_NODES * DIM * sizeof(unsigned short); // 12.8 MB
    size_t off = 0;
    float* hA = (float*)(ws + off); off += HBYTES;
    float* hB = (float*)(ws + off); off += HBYTES;
    ushort4* bf0 = (ushort4*)(ws + off); off += BFBYTES;
    ushort4* bf1 = (ushort4*)(ws + off); off += BFBYTES;
    int* row_ptr = (int*)(ws + off); off += (((size_t)(N_NODES + 1) * 4 + 255) / 256) * 256;
    int* cursor  = (int*)(ws + off); off += (((size_t)N_NODES * 4 + 255) / 256) * 256;
    int* edges   = (int*)(ws + off); off += (size_t)N_EDGES * 4;
    float* g     = (float*)(ws + off); off += (size_t)N_GRAPHS * DIM * 4;
    int* bsums   = (int*)(ws + off); off += 128 * 4;

    const int* src = eidx;
    const int* dst = eidx + N_EDGES;

    // CSR build (once, reused across 4 layers)
    hipMemsetAsync(row_ptr, 0, (size_t)N_NODES * sizeof(int), stream);
    count_kernel<<<(N_EDGES + 255) / 256, 256, 0, stream>>>(dst, row_ptr);
    scan_reduce_kernel<<<SCAN_NB, 1024, 0, stream>>>(row_ptr, bsums);
    scan_sums_kernel<<<1, 128, 0, stream>>>(bsums);
    scan_apply_kernel<<<SCAN_NB, 1024, 0, stream>>>(row_ptr, bsums, row_ptr, cursor);
    scatter_kernel<<<(N_EDGES + 255) / 256, 256, 0, stream>>>(src, dst, cursor, edges);

    // bf16 copy of x for the first layer's gather
    tobf_kernel<<<1024, 256, 0, stream>>>((const float4*)x, bf0);

    // 4 GraphConv layers, ping-pong (fp32 + bf16 streams)
    const float* hin = x;
    const ushort4* bin = bf0;
    float* fbufs[2] = {hA, hB};
    ushort4* bbufs[2] = {bf1, bf0};
    for (int l = 0; l < NLAYERS; ++l) {
        float* hout = fbufs[l & 1];
        ushort4* bout = bbufs[l & 1];
        layer_kernel<<<NB, BLOCK, 0, stream>>>(hin, (const ushort8_t*)bin, hout, bout,
                                               Wrel + (size_t)l * DIM * DIM,
                                               brel + (size_t)l * DIM,
                                               Wroot + (size_t)l * DIM * DIM,
                                               row_ptr, edges);
        hin = hout;
        bin = bout;
    }

    // global add pool
    hipMemsetAsync(g, 0, (size_t)N_GRAPHS * DIM * sizeof(float), stream);
    pool_kernel<<<256, 256, 0, stream>>>(hin, batch, g);

    // head
    head_kernel<<<(N_GRAPHS + 255) / 256, 256, 0, stream>>>(g, W1, b1, W2, b2, y);
}

// Round 10
// 516.635 us; speedup vs baseline: 5.1696x; 1.0520x over previous
//
#include <hip/hip_runtime.h>

#define N_NODES 100000
#define N_EDGES 1000000
#define DIM 64
#define N_GRAPHS 1024
#define OUT_DIM 16
#define NLAYERS 4

#define BN 64        // nodes per block in layer kernel
#define NB 1563      // ceil(N_NODES/BN)
#define BLOCK 512    // 8 waves
#define NWAVES 8
#define RPW 8        // dst rows owned per wave
#define SA 65        // LDS row stride: 65%32==1 -> 2-way alias, free

#define SCAN_NB 98   // ceil((N_NODES+1)/1024)
#define EP_CAP (N_EDGES + 7 * N_NODES)   // max padded slots = 1.7M
#define SENTSRC N_NODES                  // sentinel src -> zero row; lr bits = 0

typedef unsigned short ushort8_t __attribute__((ext_vector_type(8)));

__device__ __forceinline__ float b2f(unsigned short u) {
    union { unsigned int i; float f; } c;
    c.i = ((unsigned int)u) << 16;
    return c.f;
}
__device__ __forceinline__ unsigned short f2b(float f) {  // RNE
    union { float f; unsigned int i; } c;
    c.f = f;
    return (unsigned short)((c.i + 0x7FFFu + ((c.i >> 16) & 1u)) >> 16);
}

// ---------------- CSR build (8-aligned padded rows) ----------------
__global__ void count_kernel(const int* __restrict__ dst, int* __restrict__ counts) {
    int e = blockIdx.x * blockDim.x + threadIdx.x;
    if (e < N_EDGES) atomicAdd(&counts[dst[e]], 1);  // int atomic: native
}

__global__ __launch_bounds__(1024) void scan_reduce_kernel(const int* __restrict__ counts,
                                                           int* __restrict__ bsums) {
    int i = blockIdx.x * 1024 + threadIdx.x;
    int v = (i < N_NODES) ? ((counts[i] + 7) & ~7) : 0;  // padded degree
    __shared__ int ws_[16];
    for (int off = 32; off > 0; off >>= 1) v += __shfl_down(v, off, 64);
    if ((threadIdx.x & 63) == 0) ws_[threadIdx.x >> 6] = v;
    __syncthreads();
    if (threadIdx.x < 16) {
        int s = ws_[threadIdx.x];
        for (int off = 8; off > 0; off >>= 1) s += __shfl_down(s, off, 16);
        if (threadIdx.x == 0) bsums[blockIdx.x] = s;
    }
}

__global__ __launch_bounds__(128) void scan_sums_kernel(int* __restrict__ bsums) {
    __shared__ int t[128];
    int i = threadIdx.x;
    t[i] = (i < SCAN_NB) ? bsums[i] : 0;
    __syncthreads();
    for (int off = 1; off < 128; off <<= 1) {
        int v = (i >= off) ? t[i - off] : 0;
        __syncthreads();
        t[i] += v;
        __syncthreads();
    }
    if (i < SCAN_NB) bsums[i] = (i > 0) ? t[i - 1] : 0;  // exclusive
}

__global__ __launch_bounds__(1024) void scan_apply_kernel(const int* __restrict__ counts,
                                                          const int* __restrict__ bsums,
                                                          int* __restrict__ rp8,
                                                          int* __restrict__ cursor) {
    int i = blockIdx.x * 1024 + threadIdx.x;
    int v = (i < N_NODES) ? ((counts[i] + 7) & ~7) : 0;  // padded degree
    int lane = threadIdx.x & 63, w = threadIdx.x >> 6;
    int inc = v;
    for (int off = 1; off < 64; off <<= 1) {
        int u = __shfl_up(inc, off, 64);
        if (lane >= off) inc += u;
    }
    __shared__ int wsum[16];
    if (lane == 63) wsum[w] = inc;
    __syncthreads();
    if (threadIdx.x < 16) {
        int s = wsum[threadIdx.x];
        for (int off = 1; off < 16; off <<= 1) {
            int u = __shfl_up(s, off, 16);
            if (threadIdx.x >= off) s += u;
        }
        wsum[threadIdx.x] = s;
    }
    __syncthreads();
    int excl = inc - v + (w > 0 ? wsum[w - 1] : 0) + bsums[blockIdx.x];
    if (i <= N_NODES) rp8[i] = excl;   // in-place over counts: safe
    if (i < N_NODES) cursor[i] = excl;
}

// prefill padded edge array with sentinels; zero row N_NODES of both bf buffers
__global__ __launch_bounds__(256) void fill_kernel(int* __restrict__ edges8,
                                                   ushort4* __restrict__ bf0,
                                                   ushort4* __restrict__ bf1) {
    int stride = gridDim.x * blockDim.x;
    for (int i = blockIdx.x * blockDim.x + threadIdx.x; i < EP_CAP; i += stride)
        edges8[i] = SENTSRC;
    if (blockIdx.x == 0 && threadIdx.x < 32) {
        ushort4 z; z.x = 0; z.y = 0; z.z = 0; z.w = 0;
        if (threadIdx.x < 16) bf0[(size_t)N_NODES * 16 + threadIdx.x] = z;
        else                  bf1[(size_t)N_NODES * 16 + (threadIdx.x - 16)] = z;
    }
}

__global__ void scatter_kernel(const int* __restrict__ src, const int* __restrict__ dst,
                               int* __restrict__ cursor, int* __restrict__ edges8) {
    int e = blockIdx.x * blockDim.x + threadIdx.x;
    if (e < N_EDGES) {
        int d = dst[e];
        int pos = atomicAdd(&cursor[d], 1);         // native int atomic
        edges8[pos] = ((d & 7) << 17) | src[e];     // 3b wave-local row | 17b src
    }
}

// ---------------- x -> bf16 convert ----------------
__global__ __launch_bounds__(256) void tobf_kernel(const float4* __restrict__ in,
                                                   ushort4* __restrict__ out) {
    const int n4 = N_NODES * (DIM / 4);
    for (int i = blockIdx.x * blockDim.x + threadIdx.x; i < n4; i += gridDim.x * blockDim.x) {
        float4 v = in[i];
        ushort4 b;
        b.x = f2b(v.x); b.y = f2b(v.y); b.z = f2b(v.z); b.w = f2b(v.w);
        out[i] = b;
    }
}

__device__ __forceinline__ void flush_row(float* a, int cur, int wave, int lane,
                                          float* agg_s) {
#pragma unroll
    for (int j = 0; j < 8; ++j) {
        a[j] += __shfl_xor(a[j], 8, 64);
        a[j] += __shfl_xor(a[j], 16, 64);
        a[j] += __shfl_xor(a[j], 32, 64);
    }
    if ((lane >> 3) == 0) {  // lanes 0..7 hold dims [(lane&7)*8, +8)
#pragma unroll
        for (int j = 0; j < 8; ++j)
            agg_s[(wave * RPW + cur) * SA + (lane & 7) * 8 + j] = a[j];
    }
}

// ---------------- fused GraphConv layer ----------------
// Phase A: flat 8-aligned padded edge stream per wave (8 owned rows contiguous).
//   Every 8-edge step is one row (padding guarantees alignment); all gathers
//   independent -> 2-chunk software pipeline (4 steps/chunk): coalesced payload
//   load + __shfl distribute, gathers issued one chunk ahead. Register
//   accumulate, flush to LDS on wave-uniform row change. No atomics anywhere.
// Phase B: wave w computes dims [8w,8w+8) for all 64 nodes; weights wave-uniform.
//   x_s/agg_s both stride 65 (2-way bank alias = free; old stride-68 was 8-way).
__global__ __launch_bounds__(BLOCK) void layer_kernel(
    const float* __restrict__ hin, const ushort8_t* __restrict__ hbf_in,
    float* __restrict__ hout, ushort4* __restrict__ hbf_out,
    const float* __restrict__ Wrel, const float* __restrict__ brel,
    const float* __restrict__ Wroot,
    const int* __restrict__ rp8, const int* __restrict__ edges8) {
    __shared__ float agg_s[BN * SA];
    __shared__ float x_s[BN * SA];
    const int tid = threadIdx.x;
    const int lane = tid & 63;
    const int wave = __builtin_amdgcn_readfirstlane(tid >> 6);
    const int grp8 = lane >> 3;  // which of 8 edges in a step
    const int gl8 = lane & 7;    // ushort8 chunk within row (8 dims)
    const int node0 = blockIdx.x * BN;
    const int nvalid = min(BN, N_NODES - node0);

    // stage own x rows (coalesced global float4; LDS stride 65 -> 4x b32 writes)
    const float4* hin4g = reinterpret_cast<const float4*>(hin);
    for (int i = tid; i < nvalid * 16; i += BLOCK) {
        int nl = i >> 4, c4 = i & 15;
        float4 v = hin4g[(size_t)(node0 + nl) * 16 + c4];
        float* xp = &x_s[nl * SA + c4 * 4];
        xp[0] = v.x; xp[1] = v.y; xp[2] = v.z; xp[3] = v.w;
    }

    // zero own agg rows (same-wave ownership -> no barrier needed)
#pragma unroll
    for (int r = 0; r < RPW; ++r) agg_s[(wave * RPW + r) * SA + lane] = 0.f;

    // Phase A
    int r0c = node0 + wave * RPW; if (r0c > N_NODES) r0c = N_NODES;
    int r1c = r0c + RPW;          if (r1c > N_NODES) r1c = N_NODES;
    const int eb = rp8[r0c];
    const int nst = (rp8[r1c] - eb) >> 3;   // 8-edge steps in this wave's stream

    float a[8];
#pragma unroll
    for (int j = 0; j < 8; ++j) a[j] = 0.f;
    int cur = -1;

    if (nst > 0) {
        const int lmax = nst * 8 - 1;
        const int l32 = lane & 31;
        int pv0 = edges8[eb + min(l32, lmax)];        // payload chunk 0 (32 slots)
        int pv1 = edges8[eb + min(32 + l32, lmax)];   // payload chunk 1
        ushort8_t U0[4];
#pragma unroll
        for (int i = 0; i < 4; ++i) {                 // gathers chunk 0
            int ps = __shfl(pv0, i * 8 + grp8, 64);
            U0[i] = hbf_in[(size_t)(ps & 0x1FFFF) * 8 + gl8];
        }
        for (int c = 0; c * 4 < nst; ++c) {
            int pvn = edges8[eb + min((c + 2) * 32 + l32, lmax)];  // payloads c+2
            ushort8_t Un[4];
#pragma unroll
            for (int i = 0; i < 4; ++i) {             // gathers chunk c+1 in flight
                int ps = __shfl(pv1, i * 8 + grp8, 64);
                Un[i] = hbf_in[(size_t)(ps & 0x1FFFF) * 8 + gl8];
            }
#pragma unroll
            for (int i = 0; i < 4; ++i) {             // process chunk c
                int t = c * 4 + i;
                if (t < nst) {
                    int lr = __builtin_amdgcn_readfirstlane(__shfl(pv0, i * 8, 64)) >> 17;
                    if (lr != cur) {                  // wave-uniform row change
                        if (cur >= 0) flush_row(a, cur, wave, lane, agg_s);
                        cur = lr;
#pragma unroll
                        for (int j = 0; j < 8; ++j) a[j] = 0.f;
                    }
#pragma unroll
                    for (int j = 0; j < 8; ++j) a[j] += b2f(U0[i][j]);
                }
            }
            pv0 = pv1; pv1 = pvn;
#pragma unroll
            for (int i = 0; i < 4; ++i) U0[i] = Un[i];
        }
        if (cur >= 0) flush_row(a, cur, wave, lane, agg_s);
    }
    __syncthreads();

    // Phase B: node = lane, dim-octet = wave
    const int d0 = wave * 8;
    float out[8];
#pragma unroll
    for (int j = 0; j < 8; ++j) out[j] = brel[d0 + j];  // uniform -> scalar
    const float* ar = &agg_s[lane * SA];
    const float* xr = &x_s[lane * SA];
    for (int k = 0; k < DIM; ++k) {
        float av = ar[k];                // stride 65: 2-way alias, free
        float xv = xr[k];
        const float* wr = &Wrel[k * DIM + d0];   // wave-uniform -> s_load
        const float* wo = &Wroot[k * DIM + d0];
#pragma unroll
        for (int j = 0; j < 8; ++j)
            out[j] = fmaf(av, wr[j], fmaf(xv, wo[j], out[j]));
    }

    __syncthreads();  // all waves done reading agg_s/x_s
#pragma unroll
    for (int j = 0; j < 8; ++j) agg_s[lane * SA + d0 + j] = fmaxf(out[j], 0.f);
    __syncthreads();

    // coalesced stores: fp32 h + bf16 gather copy (transpose via agg_s)
    for (int i = tid; i < nvalid * 16; i += BLOCK) {
        int nl = i >> 4, c4 = i & 15;
        const float* xp = &agg_s[nl * SA + c4 * 4];
        float4 v = make_float4(xp[0], xp[1], xp[2], xp[3]);
        reinterpret_cast<float4*>(hout)[(size_t)(node0 + nl) * 16 + c4] = v;
        ushort4 b;
        b.x = f2b(v.x); b.y = f2b(v.y); b.z = f2b(v.z); b.w = f2b(v.w);
        hbf_out[(size_t)(node0 + nl) * 16 + c4] = b;
    }
}

// ---------------- global add pool ----------------
__global__ __launch_bounds__(256) void pool_kernel(const float* __restrict__ h,
                                                   const int* __restrict__ batch,
                                                   float* __restrict__ g) {
    int gtid = blockIdx.x * blockDim.x + threadIdx.x;
    int w = gtid >> 6;
    int lane = gtid & 63;
    const int NW = 1024;
    const int CH = (N_NODES + NW - 1) / NW;  // 98
    int nb = w * CH;
    int ne = min(nb + CH, N_NODES);
    if (nb >= ne) return;
    float acc = 0.f;
    int cur = batch[nb];
    for (int n = nb; n < ne; ++n) {
        int b = batch[n];  // wave-uniform broadcast
        if (b != cur) {
            unsafeAtomicAdd(&g[(size_t)cur * DIM + lane], acc);  // native f32 atomic
            acc = 0.f;
            cur = b;
        }
        acc += h[(size_t)n * DIM + lane];
    }
    unsafeAtomicAdd(&g[(size_t)cur * DIM + lane], acc);
}

// ---------------- classifier head ----------------
__global__ __launch_bounds__(256) void head_kernel(
    const float* __restrict__ g, const float* __restrict__ W1, const float* __restrict__ b1,
    const float* __restrict__ W2, const float* __restrict__ b2, float* __restrict__ y) {
    int gid = blockIdx.x * blockDim.x + threadIdx.x;
    if (gid >= N_GRAPHS) return;
    float t[DIM];
#pragma unroll
    for (int d = 0; d < DIM; ++d) t[d] = b1[d];
    const float4* gp = reinterpret_cast<const float4*>(g + (size_t)gid * DIM);
    for (int kk = 0; kk < DIM / 4; ++kk) {
        float4 gv = gp[kk];
        float ga[4] = {gv.x, gv.y, gv.z, gv.w};
#pragma unroll
        for (int c = 0; c < 4; ++c) {
            int k = 4 * kk + c;
            float v = ga[c];
#pragma unroll
            for (int d = 0; d < DIM; ++d) t[d] = fmaf(v, W1[k * DIM + d], t[d]);
        }
    }
#pragma unroll
    for (int d = 0; d < DIM; ++d) t[d] = fmaxf(t[d], 0.f);
    for (int o = 0; o < OUT_DIM; ++o) {
        float acc = b2[o];
#pragma unroll
        for (int d = 0; d < DIM; ++d) acc = fmaf(t[d], W2[d * OUT_DIM + o], acc);
        y[(size_t)gid * OUT_DIM + o] = acc;
    }
}

extern "C" void kernel_launch(void* const* d_in, const int* in_sizes, int n_in,
                              void* d_out, int out_size, void* d_ws, size_t ws_size,
                              hipStream_t stream) {
    const float* x     = (const float*)d_in[0];
    const int*   eidx  = (const int*)d_in[1];
    const int*   batch = (const int*)d_in[2];
    const float* Wrel  = (const float*)d_in[3];
    const float* brel  = (const float*)d_in[4];
    const float* Wroot = (const float*)d_in[5];
    const float* W1    = (const float*)d_in[6];
    const float* b1    = (const float*)d_in[7];
    const float* W2    = (const float*)d_in[8];
    const float* b2    = (const float*)d_in[9];
    float* y = (float*)d_out;

    char* ws = (char*)d_ws;
    const size_t HBYTES  = (size_t)N_NODES * DIM * sizeof(float);                // 25.6 MB
    const size_t BFBYTES = (size_t)(N_NODES + 1) * DIM * sizeof(unsigned short); // 12.8 MB + zero row
    size_t off = 0;
    float* hA = (float*)(ws + off); off += HBYTES;
    float* hB = (float*)(ws + off); off += HBYTES;
    ushort4* bf0 = (ushort4*)(ws + off); off += (BFBYTES + 255) / 256 * 256;
    ushort4* bf1 = (ushort4*)(ws + off); off += (BFBYTES + 255) / 256 * 256;
    int* rp8    = (int*)(ws + off); off += (((size_t)(N_NODES + 1) * 4 + 255) / 256) * 256;
    int* cursor = (int*)(ws + off); off += (((size_t)N_NODES * 4 + 255) / 256) * 256;
    int* edges8 = (int*)(ws + off); off += (size_t)EP_CAP * 4;
    float* g    = (float*)(ws + off); off += (size_t)N_GRAPHS * DIM * 4;
    int* bsums  = (int*)(ws + off); off += 128 * 4;

    const int* src = eidx;
    const int* dst = eidx + N_EDGES;

    // padded CSR build (once, reused across 4 layers)
    hipMemsetAsync(rp8, 0, (size_t)N_NODES * sizeof(int), stream);
    fill_kernel<<<512, 256, 0, stream>>>(edges8, bf0, bf1);
    count_kernel<<<(N_EDGES + 255) / 256, 256, 0, stream>>>(dst, rp8);
    scan_reduce_kernel<<<SCAN_NB, 1024, 0, stream>>>(rp8, bsums);
    scan_sums_kernel<<<1, 128, 0, stream>>>(bsums);
    scan_apply_kernel<<<SCAN_NB, 1024, 0, stream>>>(rp8, bsums, rp8, cursor);
    scatter_kernel<<<(N_EDGES + 255) / 256, 256, 0, stream>>>(src, dst, cursor, edges8);

    // bf16 copy of x for the first layer's gather
    tobf_kernel<<<1024, 256, 0, stream>>>((const float4*)x, bf0);

    // 4 GraphConv layers, ping-pong (fp32 + bf16 streams)
    const float* hin = x;
    const ushort4* bin = bf0;
    float* fbufs[2] = {hA, hB};
    ushort4* bbufs[2] = {bf1, bf0};
    for (int l = 0; l < NLAYERS; ++l) {
        float* hout = fbufs[l & 1];
        ushort4* bout = bbufs[l & 1];
        layer_kernel<<<NB, BLOCK, 0, stream>>>(hin, (const ushort8_t*)bin, hout, bout,
                                               Wrel + (size_t)l * DIM * DIM,
                                               brel + (size_t)l * DIM,
                                               Wroot + (size_t)l * DIM * DIM,
                                               rp8, edges8);
        hin = hout;
        bin = bout;
    }

    // global add pool
    hipMemsetAsync(g, 0, (size_t)N_GRAPHS * DIM * sizeof(float), stream);
    pool_kernel<<<256, 256, 0, stream>>>(hin, batch, g);

    // head
    head_kernel<<<(N_GRAPHS + 255) / 256, 256, 0, stream>>>(g, W1, b1, W2, b2, y);
}

// Round 11
// 458.515 us; speedup vs baseline: 5.8249x; 1.1268x over previous
//
#include <hip/hip_runtime.h>

#define N_NODES 100000
#define N_EDGES 1000000
#define DIM 64
#define N_GRAPHS 1024
#define OUT_DIM 16
#define NLAYERS 4

#define BN 64        // nodes per block in layer kernel
#define NB 1563      // ceil(N_NODES/BN)
#define BLOCK 512    // 8 waves
#define NWAVES 8
#define RPW 8        // dst rows owned per wave
#define SA 65        // LDS row stride: 65%32==1 -> 2-way alias, free
#define NGRP 12500   // N_NODES/8 wave-groups

// ---- bucket sort params ----
#define NBKT2 391            // ceil(N_NODES/256) buckets of 256 dst nodes
#define BCH 2048             // edges per pass-1 block
#define NBLK1 489            // ceil(N_EDGES/BCH)
#define SLACK 1800           // per-bucket region slack: 256*7 pad + 8
#define EPB (N_EDGES + NBKT2 * SLACK)
#define SENTSRC N_NODES      // sentinel src -> zero bf16 row

typedef unsigned short ushort8_t __attribute__((ext_vector_type(8)));

__device__ __forceinline__ float b2f(unsigned short u) {
    union { unsigned int i; float f; } c;
    c.i = ((unsigned int)u) << 16;
    return c.f;
}
__device__ __forceinline__ unsigned short f2b(float f) {  // RNE
    union { float f; unsigned int i; } c;
    c.f = f;
    return (unsigned short)((c.i + 0x7FFFu + ((c.i >> 16) & 1u)) >> 16);
}

// block-wide exclusive scan of one int per thread (256 threads); tmp = 4+ ints LDS
__device__ __forceinline__ int blk_excl_scan_256(int v, int tid, int* tmp) {
    int lane = tid & 63, w = tid >> 6;
    int inc = v;
#pragma unroll
    for (int o = 1; o < 64; o <<= 1) { int u = __shfl_up(inc, o, 64); if (lane >= o) inc += u; }
    __syncthreads();              // protect tmp from any previous use
    if (lane == 63) tmp[w] = inc;
    __syncthreads();
    if (tid == 0) { int r = 0; for (int i = 0; i < 4; ++i) { int t2 = tmp[i]; tmp[i] = r; r += t2; } }
    __syncthreads();
    return inc - v + tmp[w];
}

// ---------------- CSR build: 2-pass LDS-staged bucket sort ----------------
// (replaces count+scan*3+fill+scatter: the old random scatter wrote 65MB HBM
//  via cross-XCD false sharing of 64B lines -> 73us; all writes here are
//  either coalesced runs or block-private regions)

__global__ __launch_bounds__(256) void hist_kernel(const int* __restrict__ dst,
                                                   int* __restrict__ gsize) {
    __shared__ int h[NBKT2];
    int tid = threadIdx.x;
    for (int i = tid; i < NBKT2; i += 256) h[i] = 0;
    __syncthreads();
    int e0 = blockIdx.x * BCH;
    int nloc = min(BCH, N_EDGES - e0);
    for (int i = tid; i < nloc; i += 256) atomicAdd(&h[dst[e0 + i] >> 8], 1);  // LDS int: native
    __syncthreads();
    for (int i = tid; i < NBKT2; i += 256) if (h[i]) atomicAdd(&gsize[i], h[i]);
}

__global__ __launch_bounds__(256) void scanb_kernel(const int* __restrict__ gsize,
                                                    int* __restrict__ Abase,
                                                    int* __restrict__ Bbase) {
    __shared__ int tmp[4];
    int t = threadIdx.x;
    int a = (2 * t < NBKT2) ? gsize[2 * t] : 0;
    int b = (2 * t + 1 < NBKT2) ? gsize[2 * t + 1] : 0;
    int s = blk_excl_scan_256(a + b, t, tmp);
    if (2 * t < NBKT2) Abase[2 * t] = s;
    if (2 * t + 1 < NBKT2) Abase[2 * t + 1] = s + a;
    int a2 = (2 * t < NBKT2) ? a + SLACK : 0;
    int b2 = (2 * t + 1 < NBKT2) ? b + SLACK : 0;
    int s2 = blk_excl_scan_256(a2 + b2, t, tmp);
    if (2 * t < NBKT2) Bbase[2 * t] = s2;
    if (2 * t + 1 < NBKT2) Bbase[2 * t + 1] = s2 + a2;
}

__global__ __launch_bounds__(256) void p1_kernel(const int* __restrict__ src,
                                                 const int* __restrict__ dst,
                                                 const int* __restrict__ Abase,
                                                 int* __restrict__ Acur,
                                                 int* __restrict__ edgesA) {
    __shared__ int h[NBKT2], start[NBKT2], curb[NBKT2], resv[NBKT2], tmp[4];
    __shared__ int sortedv[BCH];
    __shared__ unsigned short sortedb[BCH];
    int tid = threadIdx.x;
    int e0 = blockIdx.x * BCH;
    int nloc = min(BCH, N_EDGES - e0);
    for (int i = tid; i < NBKT2; i += 256) h[i] = 0;
    __syncthreads();
    int myc[8], myv[8];
#pragma unroll
    for (int k = 0; k < 8; ++k) {
        int i = k * 256 + tid;
        if (i < nloc) {
            int e = e0 + i;
            int d = dst[e];
            myc[k] = d >> 8;
            myv[k] = ((d & 255) << 17) | src[e];   // 8b local dst | 17b src
            atomicAdd(&h[myc[k]], 1);
        } else myc[k] = -1;
    }
    __syncthreads();
    {   // scan h -> start (2 elems/thread over 512 slots)
        int a = (2 * tid < NBKT2) ? h[2 * tid] : 0;
        int b = (2 * tid + 1 < NBKT2) ? h[2 * tid + 1] : 0;
        int s = blk_excl_scan_256(a + b, tid, tmp);
        if (2 * tid < NBKT2) start[2 * tid] = s;
        if (2 * tid + 1 < NBKT2) start[2 * tid + 1] = s + a;
    }
    __syncthreads();
    for (int i = tid; i < NBKT2; i += 256) curb[i] = start[i];
    __syncthreads();
#pragma unroll
    for (int k = 0; k < 8; ++k) if (myc[k] >= 0) {
        int r = atomicAdd(&curb[myc[k]], 1);
        sortedv[r] = myv[k];
        sortedb[r] = (unsigned short)myc[k];
    }
    __syncthreads();
    for (int i = tid; i < NBKT2; i += 256)
        if (h[i] > 0) resv[i] = atomicAdd(&Acur[i], h[i]);   // one reservation per (block,bucket)
    __syncthreads();
    for (int i = tid; i < nloc; i += 256) {                  // coalesced run writes
        int c = sortedb[i];
        edgesA[Abase[c] + resv[c] + (i - start[c])] = sortedv[i];
    }
}

// one block per bucket: count -> 8-padded scan -> private-region scatter + pads,
// emits per-8-node-group [start,end) directly (rpS / wend8)
__global__ __launch_bounds__(256) void p2_kernel(const int* __restrict__ gsize,
                                                 const int* __restrict__ Abase,
                                                 const int* __restrict__ Bbase,
                                                 const int* __restrict__ edgesA,
                                                 int* __restrict__ edgesB,
                                                 int* __restrict__ rpS,
                                                 int* __restrict__ wend8) {
    __shared__ int cnt[256], off[256], pend[256], curx[256], tmp[4];
    int b = blockIdx.x, tid = threadIdx.x;
    int nb0 = b * 256;
    int nn = min(256, N_NODES - nb0);
    int ne = gsize[b];
    int abase = Abase[b], bbase = Bbase[b];
    cnt[tid] = 0;
    __syncthreads();
    for (int i = tid; i < ne; i += 256) atomicAdd(&cnt[edgesA[abase + i] >> 17], 1);
    __syncthreads();
    int c = cnt[tid];
    int c8 = (tid < nn) ? ((c + 7) & ~7) : 0;
    int o = blk_excl_scan_256(c8, tid, tmp);
    off[tid] = o; pend[tid] = o + c8; curx[tid] = bbase + o;
    __syncthreads();
    int gc = nn >> 3;   // N_NODES%8==0 -> nn%8==0
    if (tid < gc) {
        rpS[(nb0 >> 3) + tid] = bbase + off[tid * 8];
        wend8[(nb0 >> 3) + tid] = bbase + pend[tid * 8 + 7];
    }
    for (int i = tid; i < ne; i += 256) {
        int p = edgesA[abase + i];
        int dl = p >> 17;
        int pos = atomicAdd(&curx[dl], 1);
        edgesB[pos] = ((dl & 7) << 17) | (p & 0x1FFFF);   // wave-local row | src
    }
    __syncthreads();
    if (tid < nn) {   // sentinel pads (same row bits -> adds zero row, no spurious switch)
        int pe = bbase + pend[tid];
        int sent = ((tid & 7) << 17) | SENTSRC;
        for (int pos = curx[tid]; pos < pe; ++pos) edgesB[pos] = sent;
    }
}

// ---------------- x -> bf16 convert (+ zero sentinel rows of both bf buffers) ----------------
__global__ __launch_bounds__(256) void tobf_kernel(const float4* __restrict__ in,
                                                   ushort4* __restrict__ out,
                                                   ushort4* __restrict__ bfz1) {
    const int n4 = N_NODES * (DIM / 4);
    for (int i = blockIdx.x * blockDim.x + threadIdx.x; i < n4; i += gridDim.x * blockDim.x) {
        float4 v = in[i];
        ushort4 b;
        b.x = f2b(v.x); b.y = f2b(v.y); b.z = f2b(v.z); b.w = f2b(v.w);
        out[i] = b;
    }
    if (blockIdx.x == 0 && threadIdx.x < 32) {
        ushort4 z; z.x = 0; z.y = 0; z.z = 0; z.w = 0;
        if (threadIdx.x < 16) out[(size_t)N_NODES * 16 + threadIdx.x] = z;
        else                  bfz1[(size_t)N_NODES * 16 + (threadIdx.x - 16)] = z;
    }
}

__device__ __forceinline__ void flush_row(float* a, int cur, int wave, int lane,
                                          float* agg_s) {
#pragma unroll
    for (int j = 0; j < 8; ++j) {
        a[j] += __shfl_xor(a[j], 8, 64);
        a[j] += __shfl_xor(a[j], 16, 64);
        a[j] += __shfl_xor(a[j], 32, 64);
    }
    if ((lane >> 3) == 0) {  // lanes 0..7 hold dims [(lane&7)*8, +8)
#pragma unroll
        for (int j = 0; j < 8; ++j)
            agg_s[(wave * RPW + cur) * SA + (lane & 7) * 8 + j] = a[j];
    }
}

// ---------------- fused GraphConv layer (unchanged R10 structure) ----------------
__global__ __launch_bounds__(BLOCK) void layer_kernel(
    const float* __restrict__ hin, const ushort8_t* __restrict__ hbf_in,
    float* __restrict__ hout, ushort4* __restrict__ hbf_out,
    const float* __restrict__ Wrel, const float* __restrict__ brel,
    const float* __restrict__ Wroot,
    const int* __restrict__ rpS, const int* __restrict__ wend8,
    const int* __restrict__ edges8) {
    __shared__ float agg_s[BN * SA];
    __shared__ float x_s[BN * SA];
    const int tid = threadIdx.x;
    const int lane = tid & 63;
    const int wave = __builtin_amdgcn_readfirstlane(tid >> 6);
    const int grp8 = lane >> 3;  // which of 8 edges in a step
    const int gl8 = lane & 7;    // ushort8 chunk within row (8 dims)
    const int node0 = blockIdx.x * BN;
    const int nvalid = min(BN, N_NODES - node0);

    // stage own x rows (coalesced global float4)
    const float4* hin4g = reinterpret_cast<const float4*>(hin);
    for (int i = tid; i < nvalid * 16; i += BLOCK) {
        int nl = i >> 4, c4 = i & 15;
        float4 v = hin4g[(size_t)(node0 + nl) * 16 + c4];
        float* xp = &x_s[nl * SA + c4 * 4];
        xp[0] = v.x; xp[1] = v.y; xp[2] = v.z; xp[3] = v.w;
    }
    // zero own agg rows (same-wave ownership -> no barrier needed)
#pragma unroll
    for (int r = 0; r < RPW; ++r) agg_s[(wave * RPW + r) * SA + lane] = 0.f;

    // Phase A: flat 8-aligned padded edge stream, 2-chunk software pipeline
    const int g = blockIdx.x * 8 + wave;
    int eb = 0, nst = 0;
    if (g < NGRP) { eb = rpS[g]; nst = (wend8[g] - eb) >> 3; }

    float a[8];
#pragma unroll
    for (int j = 0; j < 8; ++j) a[j] = 0.f;
    int cur = -1;

    if (nst > 0) {
        const int lmax = nst * 8 - 1;
        const int l32 = lane & 31;
        int pv0 = edges8[eb + min(l32, lmax)];        // payload chunk 0 (32 slots)
        int pv1 = edges8[eb + min(32 + l32, lmax)];   // payload chunk 1
        ushort8_t U0[4];
#pragma unroll
        for (int i = 0; i < 4; ++i) {                 // gathers chunk 0
            int ps = __shfl(pv0, i * 8 + grp8, 64);
            U0[i] = hbf_in[(size_t)(ps & 0x1FFFF) * 8 + gl8];
        }
        for (int c = 0; c * 4 < nst; ++c) {
            int pvn = edges8[eb + min((c + 2) * 32 + l32, lmax)];  // payloads c+2
            ushort8_t Un[4];
#pragma unroll
            for (int i = 0; i < 4; ++i) {             // gathers chunk c+1 in flight
                int ps = __shfl(pv1, i * 8 + grp8, 64);
                Un[i] = hbf_in[(size_t)(ps & 0x1FFFF) * 8 + gl8];
            }
#pragma unroll
            for (int i = 0; i < 4; ++i) {             // process chunk c
                int t = c * 4 + i;
                if (t < nst) {
                    int lr = __builtin_amdgcn_readfirstlane(__shfl(pv0, i * 8, 64)) >> 17;
                    if (lr != cur) {                  // wave-uniform row change
                        if (cur >= 0) flush_row(a, cur, wave, lane, agg_s);
                        cur = lr;
#pragma unroll
                        for (int j = 0; j < 8; ++j) a[j] = 0.f;
                    }
#pragma unroll
                    for (int j = 0; j < 8; ++j) a[j] += b2f(U0[i][j]);
                }
            }
            pv0 = pv1; pv1 = pvn;
#pragma unroll
            for (int i = 0; i < 4; ++i) U0[i] = Un[i];
        }
        if (cur >= 0) flush_row(a, cur, wave, lane, agg_s);
    }
    __syncthreads();

    // Phase B: node = lane, dim-octet = wave
    const int d0 = wave * 8;
    float out[8];
#pragma unroll
    for (int j = 0; j < 8; ++j) out[j] = brel[d0 + j];  // uniform -> scalar
    const float* ar = &agg_s[lane * SA];
    const float* xr = &x_s[lane * SA];
    for (int k = 0; k < DIM; ++k) {
        float av = ar[k];                // stride 65: 2-way alias, free
        float xv = xr[k];
        const float* wr = &Wrel[k * DIM + d0];   // wave-uniform -> s_load
        const float* wo = &Wroot[k * DIM + d0];
#pragma unroll
        for (int j = 0; j < 8; ++j)
            out[j] = fmaf(av, wr[j], fmaf(xv, wo[j], out[j]));
    }

    __syncthreads();  // all waves done reading agg_s/x_s
#pragma unroll
    for (int j = 0; j < 8; ++j) agg_s[lane * SA + d0 + j] = fmaxf(out[j], 0.f);
    __syncthreads();

    // coalesced stores: fp32 h + bf16 gather copy (transpose via agg_s)
    for (int i = tid; i < nvalid * 16; i += BLOCK) {
        int nl = i >> 4, c4 = i & 15;
        const float* xp = &agg_s[nl * SA + c4 * 4];
        float4 v = make_float4(xp[0], xp[1], xp[2], xp[3]);
        reinterpret_cast<float4*>(hout)[(size_t)(node0 + nl) * 16 + c4] = v;
        ushort4 b;
        b.x = f2b(v.x); b.y = f2b(v.y); b.z = f2b(v.z); b.w = f2b(v.w);
        hbf_out[(size_t)(node0 + nl) * 16 + c4] = b;
    }
}

// ---------------- global add pool ----------------
__global__ __launch_bounds__(256) void pool_kernel(const float* __restrict__ h,
                                                   const int* __restrict__ batch,
                                                   float* __restrict__ g) {
    int gtid = blockIdx.x * blockDim.x + threadIdx.x;
    int w = gtid >> 6;
    int lane = gtid & 63;
    const int NW = 1024;
    const int CH = (N_NODES + NW - 1) / NW;  // 98
    int nb = w * CH;
    int ne = min(nb + CH, N_NODES);
    if (nb >= ne) return;
    float acc = 0.f;
    int cur = batch[nb];
    for (int n = nb; n < ne; ++n) {
        int b = batch[n];  // wave-uniform broadcast
        if (b != cur) {
            unsafeAtomicAdd(&g[(size_t)cur * DIM + lane], acc);  // native f32 atomic
            acc = 0.f;
            cur = b;
        }
        acc += h[(size_t)n * DIM + lane];
    }
    unsafeAtomicAdd(&g[(size_t)cur * DIM + lane], acc);
}

// ---------------- classifier head ----------------
__global__ __launch_bounds__(256) void head_kernel(
    const float* __restrict__ g, const float* __restrict__ W1, const float* __restrict__ b1,
    const float* __restrict__ W2, const float* __restrict__ b2, float* __restrict__ y) {
    int gid = blockIdx.x * blockDim.x + threadIdx.x;
    if (gid >= N_GRAPHS) return;
    float t[DIM];
#pragma unroll
    for (int d = 0; d < DIM; ++d) t[d] = b1[d];
    const float4* gp = reinterpret_cast<const float4*>(g + (size_t)gid * DIM);
    for (int kk = 0; kk < DIM / 4; ++kk) {
        float4 gv = gp[kk];
        float ga[4] = {gv.x, gv.y, gv.z, gv.w};
#pragma unroll
        for (int c = 0; c < 4; ++c) {
            int k = 4 * kk + c;
            float v = ga[c];
#pragma unroll
            for (int d = 0; d < DIM; ++d) t[d] = fmaf(v, W1[k * DIM + d], t[d]);
        }
    }
#pragma unroll
    for (int d = 0; d < DIM; ++d) t[d] = fmaxf(t[d], 0.f);
    for (int o = 0; o < OUT_DIM; ++o) {
        float acc = b2[o];
#pragma unroll
        for (int d = 0; d < DIM; ++d) acc = fmaf(t[d], W2[d * OUT_DIM + o], acc);
        y[(size_t)gid * OUT_DIM + o] = acc;
    }
}

extern "C" void kernel_launch(void* const* d_in, const int* in_sizes, int n_in,
                              void* d_out, int out_size, void* d_ws, size_t ws_size,
                              hipStream_t stream) {
    const float* x     = (const float*)d_in[0];
    const int*   eidx  = (const int*)d_in[1];
    const int*   batch = (const int*)d_in[2];
    const float* Wrel  = (const float*)d_in[3];
    const float* brel  = (const float*)d_in[4];
    const float* Wroot = (const float*)d_in[5];
    const float* W1    = (const float*)d_in[6];
    const float* b1    = (const float*)d_in[7];
    const float* W2    = (const float*)d_in[8];
    const float* b2    = (const float*)d_in[9];
    float* y = (float*)d_out;

    char* ws = (char*)d_ws;
    const size_t HBYTES  = (size_t)N_NODES * DIM * sizeof(float);                // 25.6 MB
    const size_t BFBYTES = (size_t)(N_NODES + 1) * DIM * sizeof(unsigned short); // 12.8 MB + zero row
    size_t off = 0;
    float* hA = (float*)(ws + off); off += HBYTES;
    float* hB = (float*)(ws + off); off += HBYTES;
    ushort4* bf0 = (ushort4*)(ws + off); off += (BFBYTES + 255) / 256 * 256;
    ushort4* bf1 = (ushort4*)(ws + off); off += (BFBYTES + 255) / 256 * 256;
    int* rpS    = (int*)(ws + off); off += (size_t)NGRP * 4;
    int* wend8  = (int*)(ws + off); off += (size_t)NGRP * 4;
    int* gsize  = (int*)(ws + off); off += (size_t)NBKT2 * 4;
    int* Acur   = (int*)(ws + off); off += (size_t)NBKT2 * 4;
    int* Abase  = (int*)(ws + off); off += (size_t)NBKT2 * 4;
    int* Bbase  = (int*)(ws + off); off += (size_t)NBKT2 * 4;
    int* edgesA = (int*)(ws + off); off += (size_t)N_EDGES * 4;
    int* edgesB = (int*)(ws + off); off += (size_t)EPB * 4;
    float* g    = (float*)(ws + off); off += (size_t)N_GRAPHS * DIM * 4;

    const int* src = eidx;
    const int* dst = eidx + N_EDGES;

    // CSR build via 2-pass bucket sort (once, reused across 4 layers)
    hipMemsetAsync(gsize, 0, (size_t)2 * NBKT2 * sizeof(int), stream);  // gsize + Acur
    hist_kernel<<<NBLK1, 256, 0, stream>>>(dst, gsize);
    scanb_kernel<<<1, 256, 0, stream>>>(gsize, Abase, Bbase);
    p1_kernel<<<NBLK1, 256, 0, stream>>>(src, dst, Abase, Acur, edgesA);
    p2_kernel<<<NBKT2, 256, 0, stream>>>(gsize, Abase, Bbase, edgesA, edgesB, rpS, wend8);

    // bf16 copy of x (+ zero sentinel rows of both bf buffers)
    tobf_kernel<<<1024, 256, 0, stream>>>((const float4*)x, bf0, bf1);

    // 4 GraphConv layers, ping-pong (fp32 + bf16 streams)
    const float* hin = x;
    const ushort4* bin = bf0;
    float* fbufs[2] = {hA, hB};
    ushort4* bbufs[2] = {bf1, bf0};
    for (int l = 0; l < NLAYERS; ++l) {
        float* hout = fbufs[l & 1];
        ushort4* bout = bbufs[l & 1];
        layer_kernel<<<NB, BLOCK, 0, stream>>>(hin, (const ushort8_t*)bin, hout, bout,
                                               Wrel + (size_t)l * DIM * DIM,
                                               brel + (size_t)l * DIM,
                                               Wroot + (size_t)l * DIM * DIM,
                                               rpS, wend8, edgesB);
        hin = hout;
        bin = bout;
    }

    // global add pool
    hipMemsetAsync(g, 0, (size_t)N_GRAPHS * DIM * sizeof(float), stream);
    pool_kernel<<<256, 256, 0, stream>>>(hin, batch, g);

    // head
    head_kernel<<<(N_GRAPHS + 255) / 256, 256, 0, stream>>>(g, W1, b1, W2, b2, y);
}

// Round 12
// 444.566 us; speedup vs baseline: 6.0077x; 1.0314x over previous
//
#include <hip/hip_runtime.h>

#define N_NODES 100000
#define N_EDGES 1000000
#define DIM 64
#define N_GRAPHS 1024
#define OUT_DIM 16
#define NLAYERS 4

#define BN 64        // nodes per block in layer kernel
#define NB 1563      // ceil(N_NODES/BN)
#define BLOCK 256    // 4 waves (512-thread blocks stalled at ~16 waves/CU)
#define NWAVES 4
#define RPW 16       // rows per wave = 2 padded 8-row groups
#define SA 65        // LDS row stride: 65%32==1 -> 2-way alias, free
#define NGRP 12500   // N_NODES/8 wave-groups

// ---- bucket sort params ----
#define NBKT2 391            // ceil(N_NODES/256) buckets of 256 dst nodes
#define BCH 2048             // edges per pass-1 block
#define NBLK1 489            // ceil(N_EDGES/BCH)
#define SLACK 1800           // per-bucket region slack: 256*7 pad + 8
#define EPB (N_EDGES + NBKT2 * SLACK)
#define SENTSRC N_NODES      // sentinel src -> zero bf16 row

typedef unsigned short ushort8_t __attribute__((ext_vector_type(8)));

__device__ __forceinline__ float b2f(unsigned short u) {
    union { unsigned int i; float f; } c;
    c.i = ((unsigned int)u) << 16;
    return c.f;
}
__device__ __forceinline__ unsigned short f2b(float f) {  // RNE
    union { float f; unsigned int i; } c;
    c.f = f;
    return (unsigned short)((c.i + 0x7FFFu + ((c.i >> 16) & 1u)) >> 16);
}

// block-wide exclusive scan of one int per thread (256 threads); tmp = 4+ ints LDS
__device__ __forceinline__ int blk_excl_scan_256(int v, int tid, int* tmp) {
    int lane = tid & 63, w = tid >> 6;
    int inc = v;
#pragma unroll
    for (int o = 1; o < 64; o <<= 1) { int u = __shfl_up(inc, o, 64); if (lane >= o) inc += u; }
    __syncthreads();              // protect tmp from any previous use
    if (lane == 63) tmp[w] = inc;
    __syncthreads();
    if (tid == 0) { int r = 0; for (int i = 0; i < 4; ++i) { int t2 = tmp[i]; tmp[i] = r; r += t2; } }
    __syncthreads();
    return inc - v + tmp[w];
}

// ---------------- CSR build: 2-pass LDS-staged bucket sort ----------------
__global__ __launch_bounds__(256) void hist_kernel(const int* __restrict__ dst,
                                                   int* __restrict__ gsize) {
    __shared__ int h[NBKT2];
    int tid = threadIdx.x;
    for (int i = tid; i < NBKT2; i += 256) h[i] = 0;
    __syncthreads();
    int e0 = blockIdx.x * BCH;
    int nloc = min(BCH, N_EDGES - e0);
    for (int i = tid; i < nloc; i += 256) atomicAdd(&h[dst[e0 + i] >> 8], 1);  // LDS int: native
    __syncthreads();
    for (int i = tid; i < NBKT2; i += 256) if (h[i]) atomicAdd(&gsize[i], h[i]);
}

__global__ __launch_bounds__(256) void scanb_kernel(const int* __restrict__ gsize,
                                                    int* __restrict__ Abase,
                                                    int* __restrict__ Bbase) {
    __shared__ int tmp[4];
    int t = threadIdx.x;
    int a = (2 * t < NBKT2) ? gsize[2 * t] : 0;
    int b = (2 * t + 1 < NBKT2) ? gsize[2 * t + 1] : 0;
    int s = blk_excl_scan_256(a + b, t, tmp);
    if (2 * t < NBKT2) Abase[2 * t] = s;
    if (2 * t + 1 < NBKT2) Abase[2 * t + 1] = s + a;
    int a2 = (2 * t < NBKT2) ? a + SLACK : 0;
    int b2 = (2 * t + 1 < NBKT2) ? b + SLACK : 0;
    int s2 = blk_excl_scan_256(a2 + b2, t, tmp);
    if (2 * t < NBKT2) Bbase[2 * t] = s2;
    if (2 * t + 1 < NBKT2) Bbase[2 * t + 1] = s2 + a2;
}

__global__ __launch_bounds__(256) void p1_kernel(const int* __restrict__ src,
                                                 const int* __restrict__ dst,
                                                 const int* __restrict__ Abase,
                                                 int* __restrict__ Acur,
                                                 int* __restrict__ edgesA) {
    __shared__ int h[NBKT2], start[NBKT2], curb[NBKT2], resv[NBKT2], tmp[4];
    __shared__ int sortedv[BCH];
    __shared__ unsigned short sortedb[BCH];
    int tid = threadIdx.x;
    int e0 = blockIdx.x * BCH;
    int nloc = min(BCH, N_EDGES - e0);
    for (int i = tid; i < NBKT2; i += 256) h[i] = 0;
    __syncthreads();
    int myc[8], myv[8];
#pragma unroll
    for (int k = 0; k < 8; ++k) {
        int i = k * 256 + tid;
        if (i < nloc) {
            int e = e0 + i;
            int d = dst[e];
            myc[k] = d >> 8;
            myv[k] = ((d & 255) << 17) | src[e];   // 8b local dst | 17b src
            atomicAdd(&h[myc[k]], 1);
        } else myc[k] = -1;
    }
    __syncthreads();
    {   // scan h -> start (2 elems/thread over 512 slots)
        int a = (2 * tid < NBKT2) ? h[2 * tid] : 0;
        int b = (2 * tid + 1 < NBKT2) ? h[2 * tid + 1] : 0;
        int s = blk_excl_scan_256(a + b, tid, tmp);
        if (2 * tid < NBKT2) start[2 * tid] = s;
        if (2 * tid + 1 < NBKT2) start[2 * tid + 1] = s + a;
    }
    __syncthreads();
    for (int i = tid; i < NBKT2; i += 256) curb[i] = start[i];
    __syncthreads();
#pragma unroll
    for (int k = 0; k < 8; ++k) if (myc[k] >= 0) {
        int r = atomicAdd(&curb[myc[k]], 1);
        sortedv[r] = myv[k];
        sortedb[r] = (unsigned short)myc[k];
    }
    __syncthreads();
    for (int i = tid; i < NBKT2; i += 256)
        if (h[i] > 0) resv[i] = atomicAdd(&Acur[i], h[i]);   // one reservation per (block,bucket)
    __syncthreads();
    for (int i = tid; i < nloc; i += 256) {                  // coalesced run writes
        int c = sortedb[i];
        edgesA[Abase[c] + resv[c] + (i - start[c])] = sortedv[i];
    }
}

// one block per bucket: count -> 8-padded scan -> private-region scatter + pads,
// emits per-8-node-group [start,end) directly (rpS / wend8)
__global__ __launch_bounds__(256) void p2_kernel(const int* __restrict__ gsize,
                                                 const int* __restrict__ Abase,
                                                 const int* __restrict__ Bbase,
                                                 const int* __restrict__ edgesA,
                                                 int* __restrict__ edgesB,
                                                 int* __restrict__ rpS,
                                                 int* __restrict__ wend8) {
    __shared__ int cnt[256], off[256], pend[256], curx[256], tmp[4];
    int b = blockIdx.x, tid = threadIdx.x;
    int nb0 = b * 256;
    int nn = min(256, N_NODES - nb0);
    int ne = gsize[b];
    int abase = Abase[b], bbase = Bbase[b];
    cnt[tid] = 0;
    __syncthreads();
    for (int i = tid; i < ne; i += 256) atomicAdd(&cnt[edgesA[abase + i] >> 17], 1);
    __syncthreads();
    int c = cnt[tid];
    int c8 = (tid < nn) ? ((c + 7) & ~7) : 0;
    int o = blk_excl_scan_256(c8, tid, tmp);
    off[tid] = o; pend[tid] = o + c8; curx[tid] = bbase + o;
    __syncthreads();
    int gc = nn >> 3;   // N_NODES%8==0 -> nn%8==0
    if (tid < gc) {
        rpS[(nb0 >> 3) + tid] = bbase + off[tid * 8];
        wend8[(nb0 >> 3) + tid] = bbase + pend[tid * 8 + 7];
    }
    for (int i = tid; i < ne; i += 256) {
        int p = edgesA[abase + i];
        int dl = p >> 17;
        int pos = atomicAdd(&curx[dl], 1);
        edgesB[pos] = ((dl & 7) << 17) | (p & 0x1FFFF);   // wave-local row | src
    }
    __syncthreads();
    if (tid < nn) {   // sentinel pads
        int pe = bbase + pend[tid];
        int sent = ((tid & 7) << 17) | SENTSRC;
        for (int pos = curx[tid]; pos < pe; ++pos) edgesB[pos] = sent;
    }
}

// ---------------- x -> bf16 convert (+ zero sentinel rows of both bf buffers) ----------------
__global__ __launch_bounds__(256) void tobf_kernel(const float4* __restrict__ in,
                                                   ushort4* __restrict__ out,
                                                   ushort4* __restrict__ bfz1) {
    const int n4 = N_NODES * (DIM / 4);
    for (int i = blockIdx.x * blockDim.x + threadIdx.x; i < n4; i += gridDim.x * blockDim.x) {
        float4 v = in[i];
        ushort4 b;
        b.x = f2b(v.x); b.y = f2b(v.y); b.z = f2b(v.z); b.w = f2b(v.w);
        out[i] = b;
    }
    if (blockIdx.x == 0 && threadIdx.x < 32) {
        ushort4 z; z.x = 0; z.y = 0; z.z = 0; z.w = 0;
        if (threadIdx.x < 16) out[(size_t)N_NODES * 16 + threadIdx.x] = z;
        else                  bfz1[(size_t)N_NODES * 16 + (threadIdx.x - 16)] = z;
    }
}

__device__ __forceinline__ void flush_row(float* a, int row, int lane, float* agg_s) {
#pragma unroll
    for (int j = 0; j < 8; ++j) {
        a[j] += __shfl_xor(a[j], 8, 64);
        a[j] += __shfl_xor(a[j], 16, 64);
        a[j] += __shfl_xor(a[j], 32, 64);
    }
    if ((lane >> 3) == 0) {  // lanes 0..7 hold dims [(lane&7)*8, +8)
#pragma unroll
        for (int j = 0; j < 8; ++j)
            agg_s[row * SA + (lane & 7) * 8 + j] = a[j];
    }
}

// ---------------- fused GraphConv layer ----------------
// 256-thread blocks (4 waves), BN=64: 8 blocks/CU cap (32 waves/CU) vs the
// 512-thread version's measured ~16 waves/CU. x_s dropped: Phase B reads its
// own x row from global (block-contiguous 16KB, L1-resident after first touch).
// Phase A: each wave streams 2 padded 8-row groups (flat 8-aligned edge stream,
// 2-chunk software pipeline, register accumulate, LDS flush on row change).
// Phase B: node = lane, dims [16w,+16) (wave-uniform -> scalar weight loads).
__global__ __launch_bounds__(BLOCK) void layer_kernel(
    const float* __restrict__ hin, const ushort8_t* __restrict__ hbf_in,
    float* __restrict__ hout, ushort4* __restrict__ hbf_out,
    const float* __restrict__ Wrel, const float* __restrict__ brel,
    const float* __restrict__ Wroot,
    const int* __restrict__ rpS, const int* __restrict__ wend8,
    const int* __restrict__ edges8) {
    __shared__ float agg_s[BN * SA];   // 16.6 KB
    const int tid = threadIdx.x;
    const int lane = tid & 63;
    const int wave = __builtin_amdgcn_readfirstlane(tid >> 6);
    const int grp8 = lane >> 3;  // which of 8 edges in a step
    const int gl8 = lane & 7;    // ushort8 chunk within row (8 dims)
    const int node0 = blockIdx.x * BN;
    const int nvalid = min(BN, N_NODES - node0);

    // zero own agg rows (same-wave ownership -> no barrier needed)
#pragma unroll
    for (int r = 0; r < RPW; ++r) agg_s[(wave * RPW + r) * SA + lane] = 0.f;

    // Phase A: two 8-row segments per wave
#pragma unroll
    for (int seg = 0; seg < 2; ++seg) {
        const int g = blockIdx.x * 8 + wave * 2 + seg;
        if (g >= NGRP) break;
        const int eb = rpS[g];
        const int nst = (wend8[g] - eb) >> 3;
        if (nst <= 0) continue;
        const int rbase = wave * RPW + seg * 8;

        float a[8];
#pragma unroll
        for (int j = 0; j < 8; ++j) a[j] = 0.f;
        int cur = -1;

        const int lmax = nst * 8 - 1;
        const int l32 = lane & 31;
        int pv0 = edges8[eb + min(l32, lmax)];        // payload chunk 0 (32 slots)
        int pv1 = edges8[eb + min(32 + l32, lmax)];   // payload chunk 1
        ushort8_t U0[4];
#pragma unroll
        for (int i = 0; i < 4; ++i) {                 // gathers chunk 0
            int ps = __shfl(pv0, i * 8 + grp8, 64);
            U0[i] = hbf_in[(size_t)(ps & 0x1FFFF) * 8 + gl8];
        }
        for (int c = 0; c * 4 < nst; ++c) {
            int pvn = edges8[eb + min((c + 2) * 32 + l32, lmax)];  // payloads c+2
            ushort8_t Un[4];
#pragma unroll
            for (int i = 0; i < 4; ++i) {             // gathers chunk c+1 in flight
                int ps = __shfl(pv1, i * 8 + grp8, 64);
                Un[i] = hbf_in[(size_t)(ps & 0x1FFFF) * 8 + gl8];
            }
#pragma unroll
            for (int i = 0; i < 4; ++i) {             // process chunk c
                int t = c * 4 + i;
                if (t < nst) {
                    int lr = __builtin_amdgcn_readfirstlane(__shfl(pv0, i * 8, 64)) >> 17;
                    if (lr != cur) {                  // wave-uniform row change
                        if (cur >= 0) flush_row(a, rbase + cur, lane, agg_s);
                        cur = lr;
#pragma unroll
                        for (int j = 0; j < 8; ++j) a[j] = 0.f;
                    }
#pragma unroll
                    for (int j = 0; j < 8; ++j) a[j] += b2f(U0[i][j]);
                }
            }
            pv0 = pv1; pv1 = pvn;
#pragma unroll
            for (int i = 0; i < 4; ++i) U0[i] = Un[i];
        }
        if (cur >= 0) flush_row(a, rbase + cur, lane, agg_s);
    }
    __syncthreads();

    // Phase B: node = lane, dims [wave*16, +16)
    const int d0 = wave * 16;
    float out[16];
#pragma unroll
    for (int j = 0; j < 16; ++j) out[j] = brel[d0 + j];  // uniform -> scalar
    const float* ar = &agg_s[lane * SA];
    const int nrow = min(node0 + lane, N_NODES - 1);     // clamp OOB lanes
    const float4* xrow4 = reinterpret_cast<const float4*>(hin + (size_t)nrow * DIM);
    for (int kk = 0; kk < 16; ++kk) {
        float4 xq = xrow4[kk];   // own row: 16KB/block, L1-resident after 1st touch
        float xa[4] = {xq.x, xq.y, xq.z, xq.w};
#pragma unroll
        for (int c = 0; c < 4; ++c) {
            int k = kk * 4 + c;
            float av = ar[k];                // stride 65: 2-way alias, free
            float xv = xa[c];
            const float* wr = &Wrel[k * DIM + d0];   // wave-uniform -> s_load
            const float* wo = &Wroot[k * DIM + d0];
#pragma unroll
            for (int j = 0; j < 16; ++j)
                out[j] = fmaf(av, wr[j], fmaf(xv, wo[j], out[j]));
        }
    }

    __syncthreads();  // all waves done reading agg_s
#pragma unroll
    for (int j = 0; j < 16; ++j) agg_s[lane * SA + d0 + j] = fmaxf(out[j], 0.f);
    __syncthreads();

    // coalesced stores: fp32 h + bf16 gather copy (transpose via agg_s)
    for (int i = tid; i < nvalid * 16; i += BLOCK) {
        int nl = i >> 4, c4 = i & 15;
        const float* xp = &agg_s[nl * SA + c4 * 4];
        float4 v = make_float4(xp[0], xp[1], xp[2], xp[3]);
        reinterpret_cast<float4*>(hout)[(size_t)(node0 + nl) * 16 + c4] = v;
        ushort4 b;
        b.x = f2b(v.x); b.y = f2b(v.y); b.z = f2b(v.z); b.w = f2b(v.w);
        hbf_out[(size_t)(node0 + nl) * 16 + c4] = b;
    }
}

// ---------------- global add pool ----------------
__global__ __launch_bounds__(256) void pool_kernel(const float* __restrict__ h,
                                                   const int* __restrict__ batch,
                                                   float* __restrict__ g) {
    int gtid = blockIdx.x * blockDim.x + threadIdx.x;
    int w = gtid >> 6;
    int lane = gtid & 63;
    const int NW = 1024;
    const int CH = (N_NODES + NW - 1) / NW;  // 98
    int nb = w * CH;
    int ne = min(nb + CH, N_NODES);
    if (nb >= ne) return;
    float acc = 0.f;
    int cur = batch[nb];
    for (int n = nb; n < ne; ++n) {
        int b = batch[n];  // wave-uniform broadcast
        if (b != cur) {
            unsafeAtomicAdd(&g[(size_t)cur * DIM + lane], acc);  // native f32 atomic
            acc = 0.f;
            cur = b;
        }
        acc += h[(size_t)n * DIM + lane];
    }
    unsafeAtomicAdd(&g[(size_t)cur * DIM + lane], acc);
}

// ---------------- classifier head ----------------
__global__ __launch_bounds__(256) void head_kernel(
    const float* __restrict__ g, const float* __restrict__ W1, const float* __restrict__ b1,
    const float* __restrict__ W2, const float* __restrict__ b2, float* __restrict__ y) {
    int gid = blockIdx.x * blockDim.x + threadIdx.x;
    if (gid >= N_GRAPHS) return;
    float t[DIM];
#pragma unroll
    for (int d = 0; d < DIM; ++d) t[d] = b1[d];
    const float4* gp = reinterpret_cast<const float4*>(g + (size_t)gid * DIM);
    for (int kk = 0; kk < DIM / 4; ++kk) {
        float4 gv = gp[kk];
        float ga[4] = {gv.x, gv.y, gv.z, gv.w};
#pragma unroll
        for (int c = 0; c < 4; ++c) {
            int k = 4 * kk + c;
            float v = ga[c];
#pragma unroll
            for (int d = 0; d < DIM; ++d) t[d] = fmaf(v, W1[k * DIM + d], t[d]);
        }
    }
#pragma unroll
    for (int d = 0; d < DIM; ++d) t[d] = fmaxf(t[d], 0.f);
    for (int o = 0; o < OUT_DIM; ++o) {
        float acc = b2[o];
#pragma unroll
        for (int d = 0; d < DIM; ++d) acc = fmaf(t[d], W2[d * OUT_DIM + o], acc);
        y[(size_t)gid * OUT_DIM + o] = acc;
    }
}

extern "C" void kernel_launch(void* const* d_in, const int* in_sizes, int n_in,
                              void* d_out, int out_size, void* d_ws, size_t ws_size,
                              hipStream_t stream) {
    const float* x     = (const float*)d_in[0];
    const int*   eidx  = (const int*)d_in[1];
    const int*   batch = (const int*)d_in[2];
    const float* Wrel  = (const float*)d_in[3];
    const float* brel  = (const float*)d_in[4];
    const float* Wroot = (const float*)d_in[5];
    const float* W1    = (const float*)d_in[6];
    const float* b1    = (const float*)d_in[7];
    const float* W2    = (const float*)d_in[8];
    const float* b2    = (const float*)d_in[9];
    float* y = (float*)d_out;

    char* ws = (char*)d_ws;
    const size_t HBYTES  = (size_t)N_NODES * DIM * sizeof(float);                // 25.6 MB
    const size_t BFBYTES = (size_t)(N_NODES + 1) * DIM * sizeof(unsigned short); // 12.8 MB + zero row
    size_t off = 0;
    float* hA = (float*)(ws + off); off += HBYTES;
    float* hB = (float*)(ws + off); off += HBYTES;
    ushort4* bf0 = (ushort4*)(ws + off); off += (BFBYTES + 255) / 256 * 256;
    ushort4* bf1 = (ushort4*)(ws + off); off += (BFBYTES + 255) / 256 * 256;
    int* rpS    = (int*)(ws + off); off += (size_t)NGRP * 4;
    int* wend8  = (int*)(ws + off); off += (size_t)NGRP * 4;
    int* gsize  = (int*)(ws + off); off += (size_t)NBKT2 * 4;
    int* Acur   = (int*)(ws + off); off += (size_t)NBKT2 * 4;
    int* Abase  = (int*)(ws + off); off += (size_t)NBKT2 * 4;
    int* Bbase  = (int*)(ws + off); off += (size_t)NBKT2 * 4;
    int* edgesA = (int*)(ws + off); off += (size_t)N_EDGES * 4;
    int* edgesB = (int*)(ws + off); off += (size_t)EPB * 4;
    float* g    = (float*)(ws + off); off += (size_t)N_GRAPHS * DIM * 4;

    const int* src = eidx;
    const int* dst = eidx + N_EDGES;

    // CSR build via 2-pass bucket sort (once, reused across 4 layers)
    hipMemsetAsync(gsize, 0, (size_t)2 * NBKT2 * sizeof(int), stream);  // gsize + Acur
    hist_kernel<<<NBLK1, 256, 0, stream>>>(dst, gsize);
    scanb_kernel<<<1, 256, 0, stream>>>(gsize, Abase, Bbase);
    p1_kernel<<<NBLK1, 256, 0, stream>>>(src, dst, Abase, Acur, edgesA);
    p2_kernel<<<NBKT2, 256, 0, stream>>>(gsize, Abase, Bbase, edgesA, edgesB, rpS, wend8);

    // bf16 copy of x (+ zero sentinel rows of both bf buffers)
    tobf_kernel<<<1024, 256, 0, stream>>>((const float4*)x, bf0, bf1);

    // 4 GraphConv layers, ping-pong (fp32 + bf16 streams)
    const float* hin = x;
    const ushort4* bin = bf0;
    float* fbufs[2] = {hA, hB};
    ushort4* bbufs[2] = {bf1, bf0};
    for (int l = 0; l < NLAYERS; ++l) {
        float* hout = fbufs[l & 1];
        ushort4* bout = bbufs[l & 1];
        layer_kernel<<<NB, BLOCK, 0, stream>>>(hin, (const ushort8_t*)bin, hout, bout,
                                               Wrel + (size_t)l * DIM * DIM,
                                               brel + (size_t)l * DIM,
                                               Wroot + (size_t)l * DIM * DIM,
                                               rpS, wend8, edgesB);
        hin = hout;
        bin = bout;
    }

    // global add pool
    hipMemsetAsync(g, 0, (size_t)N_GRAPHS * DIM * sizeof(float), stream);
    pool_kernel<<<256, 256, 0, stream>>>(hin, batch, g);

    // head
    head_kernel<<<(N_GRAPHS + 255) / 256, 256, 0, stream>>>(g, W1, b1, W2, b2, y);
}

// Round 13
// 426.184 us; speedup vs baseline: 6.2668x; 1.0431x over previous
//
#include <hip/hip_runtime.h>

#define N_NODES 100000
#define N_EDGES 1000000
#define DIM 64
#define N_GRAPHS 1024
#define OUT_DIM 16
#define NLAYERS 4

#define BN 64        // nodes per block in layer kernel
#define NB 1563      // ceil(N_NODES/BN)
#define BLOCK 256    // 4 waves
#define NWAVES 4
#define RPW 16       // rows per wave = 2 padded 8-row groups
#define SA 65        // LDS row stride: 65%32==1 -> 2-way alias, free
#define NGRP 12500   // N_NODES/8 wave-groups

// ---- bucket sort params ----
#define NBKT2 391            // ceil(N_NODES/256) buckets of 256 dst nodes
#define BCH 2048             // edges per pass-1 block
#define NBLK1 489            // ceil(N_EDGES/BCH)
#define SLACK 1800           // per-bucket region slack: 256*7 pad + 8
#define EPB (N_EDGES + NBKT2 * SLACK)
#define SENTSRC N_NODES      // sentinel src -> zero bf16 row

typedef unsigned short ushort8_t __attribute__((ext_vector_type(8)));

__device__ __forceinline__ float b2f(unsigned short u) {
    union { unsigned int i; float f; } c;
    c.i = ((unsigned int)u) << 16;
    return c.f;
}
__device__ __forceinline__ unsigned short f2b(float f) {  // RNE
    union { float f; unsigned int i; } c;
    c.f = f;
    return (unsigned short)((c.i + 0x7FFFu + ((c.i >> 16) & 1u)) >> 16);
}

// block-wide exclusive scan of one int per thread (256 threads); tmp = 4+ ints LDS
__device__ __forceinline__ int blk_excl_scan_256(int v, int tid, int* tmp) {
    int lane = tid & 63, w = tid >> 6;
    int inc = v;
#pragma unroll
    for (int o = 1; o < 64; o <<= 1) { int u = __shfl_up(inc, o, 64); if (lane >= o) inc += u; }
    __syncthreads();              // protect tmp from any previous use
    if (lane == 63) tmp[w] = inc;
    __syncthreads();
    if (tid == 0) { int r = 0; for (int i = 0; i < 4; ++i) { int t2 = tmp[i]; tmp[i] = r; r += t2; } }
    __syncthreads();
    return inc - v + tmp[w];
}

// ---------------- prep: per-block histogram + tobf + zero g + sentinel rows ----------------
// Per-block hist rows (no global atomics -> no memset needed); tobf and g-zeroing
// folded in as independent grid-stride work (saves 2 launches).
__global__ __launch_bounds__(256) void prep_kernel(const int* __restrict__ dst,
                                                   int* __restrict__ hblk,
                                                   const float4* __restrict__ x,
                                                   ushort4* __restrict__ bf0,
                                                   ushort4* __restrict__ bf1,
                                                   float* __restrict__ g) {
    __shared__ int h[NBKT2];
    int tid = threadIdx.x;
    for (int i = tid; i < NBKT2; i += 256) h[i] = 0;
    __syncthreads();
    int e0 = blockIdx.x * BCH;
    int nloc = min(BCH, N_EDGES - e0);
    for (int i = tid; i < nloc; i += 256) atomicAdd(&h[dst[e0 + i] >> 8], 1);  // LDS int: native

    // tobf (independent)
    const int n4 = N_NODES * (DIM / 4);
    for (int i = blockIdx.x * 256 + tid; i < n4; i += NBLK1 * 256) {
        float4 v = x[i];
        ushort4 b;
        b.x = f2b(v.x); b.y = f2b(v.y); b.z = f2b(v.z); b.w = f2b(v.w);
        bf0[i] = b;
    }
    // zero g (independent; pool is fused into last layer)
    const int g4 = N_GRAPHS * (DIM / 4);
    float4 z4 = make_float4(0.f, 0.f, 0.f, 0.f);
    for (int i = blockIdx.x * 256 + tid; i < g4; i += NBLK1 * 256)
        reinterpret_cast<float4*>(g)[i] = z4;
    // zero sentinel rows of both bf buffers
    if (blockIdx.x == 0 && tid < 32) {
        ushort4 z; z.x = 0; z.y = 0; z.z = 0; z.w = 0;
        if (tid < 16) bf0[(size_t)N_NODES * 16 + tid] = z;
        else          bf1[(size_t)N_NODES * 16 + (tid - 16)] = z;
    }
    __syncthreads();
    for (int i = tid; i < NBKT2; i += 256) hblk[(size_t)blockIdx.x * NBKT2 + i] = h[i];
}

// single block: per-bucket block-prefix (in-place over hblk, 8-unrolled to keep
// loads in flight) + bucket totals -> gsize, Abase, Bbase
__global__ __launch_bounds__(256) void scanb_kernel(int* __restrict__ hblk,
                                                    int* __restrict__ Abase,
                                                    int* __restrict__ Bbase,
                                                    int* __restrict__ gsize) {
    __shared__ int tmp[4];
    int t = threadIdx.x;
    int c0 = 2 * t, c1 = 2 * t + 1;
    bool v0ok = c0 < NBKT2, v1ok = c1 < NBKT2;
    int run0 = 0, run1 = 0;
    for (int b = 0; b < NBLK1; b += 8) {
        int a0[8], a1[8];
#pragma unroll
        for (int k = 0; k < 8; ++k) {      // 16 independent loads in flight
            int bb = b + k;
            a0[k] = (bb < NBLK1 && v0ok) ? hblk[(size_t)bb * NBKT2 + c0] : 0;
            a1[k] = (bb < NBLK1 && v1ok) ? hblk[(size_t)bb * NBKT2 + c1] : 0;
        }
#pragma unroll
        for (int k = 0; k < 8; ++k) {
            int bb = b + k;
            if (bb < NBLK1 && v0ok) hblk[(size_t)bb * NBKT2 + c0] = run0;
            if (bb < NBLK1 && v1ok) hblk[(size_t)bb * NBKT2 + c1] = run1;
            run0 += a0[k]; run1 += a1[k];
        }
    }
    int s = blk_excl_scan_256(run0 + run1, t, tmp);
    if (v0ok) { Abase[c0] = s; gsize[c0] = run0; }
    if (v1ok) { Abase[c1] = s + run0; gsize[c1] = run1; }
    int a2 = v0ok ? run0 + SLACK : 0;
    int b2 = v1ok ? run1 + SLACK : 0;
    int s2 = blk_excl_scan_256(a2 + b2, t, tmp);
    if (v0ok) Bbase[c0] = s2;
    if (v1ok) Bbase[c1] = s2 + a2;
}

__global__ __launch_bounds__(256) void p1_kernel(const int* __restrict__ src,
                                                 const int* __restrict__ dst,
                                                 const int* __restrict__ Abase,
                                                 const int* __restrict__ hblk,
                                                 int* __restrict__ edgesA) {
    __shared__ int h[NBKT2], start[NBKT2], curb[NBKT2], resv[NBKT2], tmp[4];
    __shared__ int sortedv[BCH];
    __shared__ unsigned short sortedb[BCH];
    int tid = threadIdx.x;
    int e0 = blockIdx.x * BCH;
    int nloc = min(BCH, N_EDGES - e0);
    for (int i = tid; i < NBKT2; i += 256) h[i] = 0;
    __syncthreads();
    int myc[8], myv[8];
#pragma unroll
    for (int k = 0; k < 8; ++k) {
        int i = k * 256 + tid;
        if (i < nloc) {
            int e = e0 + i;
            int d = dst[e];
            myc[k] = d >> 8;
            myv[k] = ((d & 255) << 17) | src[e];   // 8b local dst | 17b src
            atomicAdd(&h[myc[k]], 1);
        } else myc[k] = -1;
    }
    __syncthreads();
    {   // scan h -> start (2 elems/thread over 512 slots)
        int a = (2 * tid < NBKT2) ? h[2 * tid] : 0;
        int b = (2 * tid + 1 < NBKT2) ? h[2 * tid + 1] : 0;
        int s = blk_excl_scan_256(a + b, tid, tmp);
        if (2 * tid < NBKT2) start[2 * tid] = s;
        if (2 * tid + 1 < NBKT2) start[2 * tid + 1] = s + a;
    }
    __syncthreads();
    for (int i = tid; i < NBKT2; i += 256) curb[i] = start[i];
    __syncthreads();
#pragma unroll
    for (int k = 0; k < 8; ++k) if (myc[k] >= 0) {
        int r = atomicAdd(&curb[myc[k]], 1);
        sortedv[r] = myv[k];
        sortedb[r] = (unsigned short)myc[k];
    }
    __syncthreads();
    // reservation = precomputed block-prefix (scanb) -- no global atomics
    for (int i = tid; i < NBKT2; i += 256) resv[i] = hblk[(size_t)blockIdx.x * NBKT2 + i];
    __syncthreads();
    for (int i = tid; i < nloc; i += 256) {                  // coalesced run writes
        int c = sortedb[i];
        edgesA[Abase[c] + resv[c] + (i - start[c])] = sortedv[i];
    }
}

// one block per bucket: count -> 8-padded scan -> private-region scatter + pads,
// emits per-8-node-group [start,end) directly (rpS / wend8)
__global__ __launch_bounds__(256) void p2_kernel(const int* __restrict__ gsize,
                                                 const int* __restrict__ Abase,
                                                 const int* __restrict__ Bbase,
                                                 const int* __restrict__ edgesA,
                                                 int* __restrict__ edgesB,
                                                 int* __restrict__ rpS,
                                                 int* __restrict__ wend8) {
    __shared__ int cnt[256], off[256], pend[256], curx[256], tmp[4];
    int b = blockIdx.x, tid = threadIdx.x;
    int nb0 = b * 256;
    int nn = min(256, N_NODES - nb0);
    int ne = gsize[b];
    int abase = Abase[b], bbase = Bbase[b];
    cnt[tid] = 0;
    __syncthreads();
    for (int i = tid; i < ne; i += 256) atomicAdd(&cnt[edgesA[abase + i] >> 17], 1);
    __syncthreads();
    int c = cnt[tid];
    int c8 = (tid < nn) ? ((c + 7) & ~7) : 0;
    int o = blk_excl_scan_256(c8, tid, tmp);
    off[tid] = o; pend[tid] = o + c8; curx[tid] = bbase + o;
    __syncthreads();
    int gc = nn >> 3;
    if (tid < gc) {
        rpS[(nb0 >> 3) + tid] = bbase + off[tid * 8];
        wend8[(nb0 >> 3) + tid] = bbase + pend[tid * 8 + 7];
    }
    for (int i = tid; i < ne; i += 256) {
        int p = edgesA[abase + i];
        int dl = p >> 17;
        int pos = atomicAdd(&curx[dl], 1);
        edgesB[pos] = ((dl & 7) << 17) | (p & 0x1FFFF);   // wave-local row | src
    }
    __syncthreads();
    if (tid < nn) {   // sentinel pads
        int pe = bbase + pend[tid];
        int sent = ((tid & 7) << 17) | SENTSRC;
        for (int pos = curx[tid]; pos < pe; ++pos) edgesB[pos] = sent;
    }
}

__device__ __forceinline__ void flush_row(float* a, int row, int lane, float* agg_s) {
#pragma unroll
    for (int j = 0; j < 8; ++j) {
        a[j] += __shfl_xor(a[j], 8, 64);
        a[j] += __shfl_xor(a[j], 16, 64);
        a[j] += __shfl_xor(a[j], 32, 64);
    }
    if ((lane >> 3) == 0) {
#pragma unroll
        for (int j = 0; j < 8; ++j)
            agg_s[row * SA + (lane & 7) * 8 + j] = a[j];
    }
}

// ---------------- fused GraphConv layer (R12 structure; LAST fuses the pool) ----
// LAST: skip the 38MB hout/bf stores; wave 0 run-accumulates the block's 64
// relu'd rows (in agg_s) by sorted batch -> ~2 unsafeAtomicAdd rows into g.
template <bool LAST>
__global__ __launch_bounds__(BLOCK) void layer_kernel(
    const float* __restrict__ hin, const ushort8_t* __restrict__ hbf_in,
    float* __restrict__ hout, ushort4* __restrict__ hbf_out,
    const float* __restrict__ Wrel, const float* __restrict__ brel,
    const float* __restrict__ Wroot,
    const int* __restrict__ rpS, const int* __restrict__ wend8,
    const int* __restrict__ edges8,
    const int* __restrict__ batch, float* __restrict__ g) {
    __shared__ float agg_s[BN * SA];   // 16.6 KB
    const int tid = threadIdx.x;
    const int lane = tid & 63;
    const int wave = __builtin_amdgcn_readfirstlane(tid >> 6);
    const int grp8 = lane >> 3;
    const int gl8 = lane & 7;
    const int node0 = blockIdx.x * BN;
    const int nvalid = min(BN, N_NODES - node0);

#pragma unroll
    for (int r = 0; r < RPW; ++r) agg_s[(wave * RPW + r) * SA + lane] = 0.f;

    // Phase A: two 8-row segments per wave
#pragma unroll
    for (int seg = 0; seg < 2; ++seg) {
        const int gg = blockIdx.x * 8 + wave * 2 + seg;
        if (gg >= NGRP) break;
        const int eb = rpS[gg];
        const int nst = (wend8[gg] - eb) >> 3;
        if (nst <= 0) continue;
        const int rbase = wave * RPW + seg * 8;

        float a[8];
#pragma unroll
        for (int j = 0; j < 8; ++j) a[j] = 0.f;
        int cur = -1;

        const int lmax = nst * 8 - 1;
        const int l32 = lane & 31;
        int pv0 = edges8[eb + min(l32, lmax)];
        int pv1 = edges8[eb + min(32 + l32, lmax)];
        ushort8_t U0[4];
#pragma unroll
        for (int i = 0; i < 4; ++i) {
            int ps = __shfl(pv0, i * 8 + grp8, 64);
            U0[i] = hbf_in[(size_t)(ps & 0x1FFFF) * 8 + gl8];
        }
        for (int c = 0; c * 4 < nst; ++c) {
            int pvn = edges8[eb + min((c + 2) * 32 + l32, lmax)];
            ushort8_t Un[4];
#pragma unroll
            for (int i = 0; i < 4; ++i) {
                int ps = __shfl(pv1, i * 8 + grp8, 64);
                Un[i] = hbf_in[(size_t)(ps & 0x1FFFF) * 8 + gl8];
            }
#pragma unroll
            for (int i = 0; i < 4; ++i) {
                int t = c * 4 + i;
                if (t < nst) {
                    int lr = __builtin_amdgcn_readfirstlane(__shfl(pv0, i * 8, 64)) >> 17;
                    if (lr != cur) {
                        if (cur >= 0) flush_row(a, rbase + cur, lane, agg_s);
                        cur = lr;
#pragma unroll
                        for (int j = 0; j < 8; ++j) a[j] = 0.f;
                    }
#pragma unroll
                    for (int j = 0; j < 8; ++j) a[j] += b2f(U0[i][j]);
                }
            }
            pv0 = pv1; pv1 = pvn;
#pragma unroll
            for (int i = 0; i < 4; ++i) U0[i] = Un[i];
        }
        if (cur >= 0) flush_row(a, rbase + cur, lane, agg_s);
    }
    __syncthreads();

    // Phase B: node = lane, dims [wave*16, +16)
    const int d0 = wave * 16;
    float out[16];
#pragma unroll
    for (int j = 0; j < 16; ++j) out[j] = brel[d0 + j];
    const float* ar = &agg_s[lane * SA];
    const int nrow = min(node0 + lane, N_NODES - 1);
    const float4* xrow4 = reinterpret_cast<const float4*>(hin + (size_t)nrow * DIM);
    for (int kk = 0; kk < 16; ++kk) {
        float4 xq = xrow4[kk];
        float xa[4] = {xq.x, xq.y, xq.z, xq.w};
#pragma unroll
        for (int c = 0; c < 4; ++c) {
            int k = kk * 4 + c;
            float av = ar[k];
            float xv = xa[c];
            const float* wr = &Wrel[k * DIM + d0];
            const float* wo = &Wroot[k * DIM + d0];
#pragma unroll
            for (int j = 0; j < 16; ++j)
                out[j] = fmaf(av, wr[j], fmaf(xv, wo[j], out[j]));
        }
    }

    __syncthreads();
#pragma unroll
    for (int j = 0; j < 16; ++j) agg_s[lane * SA + d0 + j] = fmaxf(out[j], 0.f);
    __syncthreads();

    if (LAST) {
        // fused global_add_pool: wave 0, lane = dim; batch is sorted
        if (wave == 0) {
            float acc = 0.f;
            int cur = batch[node0];
            for (int nl = 0; nl < nvalid; ++nl) {
                int bv = batch[node0 + nl];          // wave-uniform scalar
                float v = agg_s[nl * SA + lane];
                if (bv != cur) {
                    unsafeAtomicAdd(&g[(size_t)cur * DIM + lane], acc);
                    acc = 0.f; cur = bv;
                }
                acc += v;
            }
            unsafeAtomicAdd(&g[(size_t)cur * DIM + lane], acc);
        }
    } else {
        // coalesced stores: fp32 h + bf16 gather copy (transpose via agg_s)
        for (int i = tid; i < nvalid * 16; i += BLOCK) {
            int nl = i >> 4, c4 = i & 15;
            const float* xp = &agg_s[nl * SA + c4 * 4];
            float4 v = make_float4(xp[0], xp[1], xp[2], xp[3]);
            reinterpret_cast<float4*>(hout)[(size_t)(node0 + nl) * 16 + c4] = v;
            ushort4 b;
            b.x = f2b(v.x); b.y = f2b(v.y); b.z = f2b(v.z); b.w = f2b(v.w);
            hbf_out[(size_t)(node0 + nl) * 16 + c4] = b;
        }
    }
}

// ---------------- classifier head ----------------
__global__ __launch_bounds__(256) void head_kernel(
    const float* __restrict__ g, const float* __restrict__ W1, const float* __restrict__ b1,
    const float* __restrict__ W2, const float* __restrict__ b2, float* __restrict__ y) {
    int gid = blockIdx.x * blockDim.x + threadIdx.x;
    if (gid >= N_GRAPHS) return;
    float t[DIM];
#pragma unroll
    for (int d = 0; d < DIM; ++d) t[d] = b1[d];
    const float4* gp = reinterpret_cast<const float4*>(g + (size_t)gid * DIM);
    for (int kk = 0; kk < DIM / 4; ++kk) {
        float4 gv = gp[kk];
        float ga[4] = {gv.x, gv.y, gv.z, gv.w};
#pragma unroll
        for (int c = 0; c < 4; ++c) {
            int k = 4 * kk + c;
            float v = ga[c];
#pragma unroll
            for (int d = 0; d < DIM; ++d) t[d] = fmaf(v, W1[k * DIM + d], t[d]);
        }
    }
#pragma unroll
    for (int d = 0; d < DIM; ++d) t[d] = fmaxf(t[d], 0.f);
    for (int o = 0; o < OUT_DIM; ++o) {
        float acc = b2[o];
#pragma unroll
        for (int d = 0; d < DIM; ++d) acc = fmaf(t[d], W2[d * OUT_DIM + o], acc);
        y[(size_t)gid * OUT_DIM + o] = acc;
    }
}

extern "C" void kernel_launch(void* const* d_in, const int* in_sizes, int n_in,
                              void* d_out, int out_size, void* d_ws, size_t ws_size,
                              hipStream_t stream) {
    const float* x     = (const float*)d_in[0];
    const int*   eidx  = (const int*)d_in[1];
    const int*   batch = (const int*)d_in[2];
    const float* Wrel  = (const float*)d_in[3];
    const float* brel  = (const float*)d_in[4];
    const float* Wroot = (const float*)d_in[5];
    const float* W1    = (const float*)d_in[6];
    const float* b1    = (const float*)d_in[7];
    const float* W2    = (const float*)d_in[8];
    const float* b2    = (const float*)d_in[9];
    float* y = (float*)d_out;

    char* ws = (char*)d_ws;
    const size_t HBYTES  = (size_t)N_NODES * DIM * sizeof(float);                // 25.6 MB
    const size_t BFBYTES = (size_t)(N_NODES + 1) * DIM * sizeof(unsigned short); // 12.8 MB + zero row
    size_t off = 0;
    float* hA = (float*)(ws + off); off += HBYTES;
    float* hB = (float*)(ws + off); off += HBYTES;
    ushort4* bf0 = (ushort4*)(ws + off); off += (BFBYTES + 255) / 256 * 256;
    ushort4* bf1 = (ushort4*)(ws + off); off += (BFBYTES + 255) / 256 * 256;
    int* rpS    = (int*)(ws + off); off += (size_t)NGRP * 4;
    int* wend8  = (int*)(ws + off); off += (size_t)NGRP * 4;
    int* gsize  = (int*)(ws + off); off += (size_t)NBKT2 * 4;
    int* Abase  = (int*)(ws + off); off += (size_t)NBKT2 * 4;
    int* Bbase  = (int*)(ws + off); off += (size_t)NBKT2 * 4;
    int* hblk   = (int*)(ws + off); off += (size_t)NBLK1 * NBKT2 * 4;  // 765 KB
    int* edgesA = (int*)(ws + off); off += (size_t)N_EDGES * 4;
    int* edgesB = (int*)(ws + off); off += (size_t)EPB * 4;
    float* g    = (float*)(ws + off); off += (size_t)N_GRAPHS * DIM * 4;

    const int* src = eidx;
    const int* dst = eidx + N_EDGES;

    // CSR build (9 launches total; no memsets, no tobf, no pool kernel)
    prep_kernel<<<NBLK1, 256, 0, stream>>>(dst, hblk, (const float4*)x, bf0, bf1, g);
    scanb_kernel<<<1, 256, 0, stream>>>(hblk, Abase, Bbase, gsize);
    p1_kernel<<<NBLK1, 256, 0, stream>>>(src, dst, Abase, hblk, edgesA);
    p2_kernel<<<NBKT2, 256, 0, stream>>>(gsize, Abase, Bbase, edgesA, edgesB, rpS, wend8);

    // 4 GraphConv layers, ping-pong (fp32 + bf16 streams); last fuses pool
    layer_kernel<false><<<NB, BLOCK, 0, stream>>>(x, (const ushort8_t*)bf0, hA, bf1,
        Wrel + 0 * DIM * DIM, brel + 0 * DIM, Wroot + 0 * DIM * DIM,
        rpS, wend8, edgesB, batch, g);
    layer_kernel<false><<<NB, BLOCK, 0, stream>>>(hA, (const ushort8_t*)bf1, hB, bf0,
        Wrel + 1 * DIM * DIM, brel + 1 * DIM, Wroot + 1 * DIM * DIM,
        rpS, wend8, edgesB, batch, g);
    layer_kernel<false><<<NB, BLOCK, 0, stream>>>(hB, (const ushort8_t*)bf0, hA, bf1,
        Wrel + 2 * DIM * DIM, brel + 2 * DIM, Wroot + 2 * DIM * DIM,
        rpS, wend8, edgesB, batch, g);
    layer_kernel<true><<<NB, BLOCK, 0, stream>>>(hA, (const ushort8_t*)bf1, hB, bf0,
        Wrel + 3 * DIM * DIM, brel + 3 * DIM, Wroot + 3 * DIM * DIM,
        rpS, wend8, edgesB, batch, g);

    // head
    head_kernel<<<(N_GRAPHS + 255) / 256, 256, 0, stream>>>(g, W1, b1, W2, b2, y);
}

// Round 14
// 370.966 us; speedup vs baseline: 7.1996x; 1.1488x over previous
//
#include <hip/hip_runtime.h>

#define N_NODES 100000
#define N_EDGES 1000000
#define DIM 64
#define N_GRAPHS 1024
#define OUT_DIM 16
#define NLAYERS 4

#define BN 64        // nodes per block in layer kernel
#define NB 1563      // ceil(N_NODES/BN)
#define BLOCK 256    // 4 waves
#define NWAVES 4
#define RPW 16       // rows per wave = 2 padded 8-row groups
#define SA 65        // LDS row stride: 65%32==1 -> 2-way alias, free
#define NGRP 12500   // N_NODES/8 wave-groups

// ---- bucket sort params ----
#define NBKT2 391            // ceil(N_NODES/256) buckets of 256 dst nodes
#define BCH 2048             // edges per pass-1 block
#define NBLK1 489            // ceil(N_EDGES/BCH)
#define SLACK 1800           // per-bucket region slack: 256*7 pad + 8
#define EPB (N_EDGES + NBKT2 * SLACK)
#define SENTSRC N_NODES      // sentinel src -> zero bf16 row

typedef unsigned short ushort8_t __attribute__((ext_vector_type(8)));

__device__ __forceinline__ float b2f(unsigned short u) {
    union { unsigned int i; float f; } c;
    c.i = ((unsigned int)u) << 16;
    return c.f;
}
__device__ __forceinline__ unsigned short f2b(float f) {  // RNE
    union { float f; unsigned int i; } c;
    c.f = f;
    return (unsigned short)((c.i + 0x7FFFu + ((c.i >> 16) & 1u)) >> 16);
}

// block-wide exclusive scan of one int per thread (256 threads); tmp = 4+ ints LDS
__device__ __forceinline__ int blk_excl_scan_256(int v, int tid, int* tmp) {
    int lane = tid & 63, w = tid >> 6;
    int inc = v;
#pragma unroll
    for (int o = 1; o < 64; o <<= 1) { int u = __shfl_up(inc, o, 64); if (lane >= o) inc += u; }
    __syncthreads();              // protect tmp from any previous use
    if (lane == 63) tmp[w] = inc;
    __syncthreads();
    if (tid == 0) { int r = 0; for (int i = 0; i < 4; ++i) { int t2 = tmp[i]; tmp[i] = r; r += t2; } }
    __syncthreads();
    return inc - v + tmp[w];
}

// ---------------- prep: per-block histogram + tobf + zero g + sentinel rows ----------------
__global__ __launch_bounds__(256) void prep_kernel(const int* __restrict__ dst,
                                                   int* __restrict__ hblk,
                                                   const float4* __restrict__ x,
                                                   ushort4* __restrict__ bf0,
                                                   ushort4* __restrict__ bf1,
                                                   float* __restrict__ g) {
    __shared__ int h[NBKT2];
    int tid = threadIdx.x;
    for (int i = tid; i < NBKT2; i += 256) h[i] = 0;
    __syncthreads();
    int e0 = blockIdx.x * BCH;
    int nloc = min(BCH, N_EDGES - e0);
    for (int i = tid; i < nloc; i += 256) atomicAdd(&h[dst[e0 + i] >> 8], 1);  // LDS int: native

    // tobf (independent)
    const int n4 = N_NODES * (DIM / 4);
    for (int i = blockIdx.x * 256 + tid; i < n4; i += NBLK1 * 256) {
        float4 v = x[i];
        ushort4 b;
        b.x = f2b(v.x); b.y = f2b(v.y); b.z = f2b(v.z); b.w = f2b(v.w);
        bf0[i] = b;
    }
    // zero g (independent; pool is fused into last layer)
    const int g4 = N_GRAPHS * (DIM / 4);
    float4 z4 = make_float4(0.f, 0.f, 0.f, 0.f);
    for (int i = blockIdx.x * 256 + tid; i < g4; i += NBLK1 * 256)
        reinterpret_cast<float4*>(g)[i] = z4;
    // zero sentinel rows of both bf buffers
    if (blockIdx.x == 0 && tid < 32) {
        ushort4 z; z.x = 0; z.y = 0; z.z = 0; z.w = 0;
        if (tid < 16) bf0[(size_t)N_NODES * 16 + tid] = z;
        else          bf1[(size_t)N_NODES * 16 + (tid - 16)] = z;
    }
    __syncthreads();
    for (int i = tid; i < NBKT2; i += 256) hblk[(size_t)blockIdx.x * NBKT2 + i] = h[i];
}

// ---- column scan: one block per bucket, scan the 489 per-block counts ----
// (replaces the single-block scanb walk: 765KB column-strided from ONE CU was
//  latency-serialized at ~12GB/s = 65us; here 391 blocks x 512 loads in flight)
__global__ __launch_bounds__(256) void colscan_kernel(int* __restrict__ hblk,
                                                      int* __restrict__ gsize) {
    __shared__ int tmp[4];
    int c = blockIdx.x, t = threadIdx.x;
    int i0 = 2 * t, i1 = 2 * t + 1;
    int a = (i0 < NBLK1) ? hblk[(size_t)i0 * NBKT2 + c] : 0;
    int b = (i1 < NBLK1) ? hblk[(size_t)i1 * NBKT2 + c] : 0;
    int s = blk_excl_scan_256(a + b, t, tmp);
    if (i0 < NBLK1) hblk[(size_t)i0 * NBKT2 + c] = s;
    if (i1 < NBLK1) hblk[(size_t)i1 * NBKT2 + c] = s + a;
    if (t == 255) gsize[c] = s + a + b;   // column total
}

// tiny single block: scan 391 bucket totals -> Abase, Bbase
__global__ __launch_bounds__(256) void scanb2_kernel(const int* __restrict__ gsize,
                                                     int* __restrict__ Abase,
                                                     int* __restrict__ Bbase) {
    __shared__ int tmp[4];
    int t = threadIdx.x;
    int c0 = 2 * t, c1 = 2 * t + 1;
    int a = (c0 < NBKT2) ? gsize[c0] : 0;
    int b = (c1 < NBKT2) ? gsize[c1] : 0;
    int s = blk_excl_scan_256(a + b, t, tmp);
    if (c0 < NBKT2) Abase[c0] = s;
    if (c1 < NBKT2) Abase[c1] = s + a;
    int a2 = (c0 < NBKT2) ? a + SLACK : 0;
    int b2 = (c1 < NBKT2) ? b + SLACK : 0;
    int s2 = blk_excl_scan_256(a2 + b2, t, tmp);
    if (c0 < NBKT2) Bbase[c0] = s2;
    if (c1 < NBKT2) Bbase[c1] = s2 + a2;
}

__global__ __launch_bounds__(256) void p1_kernel(const int* __restrict__ src,
                                                 const int* __restrict__ dst,
                                                 const int* __restrict__ Abase,
                                                 const int* __restrict__ hblk,
                                                 int* __restrict__ edgesA) {
    __shared__ int h[NBKT2], start[NBKT2], curb[NBKT2], resv[NBKT2], tmp[4];
    __shared__ int sortedv[BCH];
    __shared__ unsigned short sortedb[BCH];
    int tid = threadIdx.x;
    int e0 = blockIdx.x * BCH;
    int nloc = min(BCH, N_EDGES - e0);
    for (int i = tid; i < NBKT2; i += 256) h[i] = 0;
    __syncthreads();
    int myc[8], myv[8];
#pragma unroll
    for (int k = 0; k < 8; ++k) {
        int i = k * 256 + tid;
        if (i < nloc) {
            int e = e0 + i;
            int d = dst[e];
            myc[k] = d >> 8;
            myv[k] = ((d & 255) << 17) | src[e];   // 8b local dst | 17b src
            atomicAdd(&h[myc[k]], 1);
        } else myc[k] = -1;
    }
    __syncthreads();
    {   // scan h -> start (2 elems/thread over 512 slots)
        int a = (2 * tid < NBKT2) ? h[2 * tid] : 0;
        int b = (2 * tid + 1 < NBKT2) ? h[2 * tid + 1] : 0;
        int s = blk_excl_scan_256(a + b, tid, tmp);
        if (2 * tid < NBKT2) start[2 * tid] = s;
        if (2 * tid + 1 < NBKT2) start[2 * tid + 1] = s + a;
    }
    __syncthreads();
    for (int i = tid; i < NBKT2; i += 256) curb[i] = start[i];
    __syncthreads();
#pragma unroll
    for (int k = 0; k < 8; ++k) if (myc[k] >= 0) {
        int r = atomicAdd(&curb[myc[k]], 1);
        sortedv[r] = myv[k];
        sortedb[r] = (unsigned short)myc[k];
    }
    __syncthreads();
    // reservation = precomputed block-prefix (colscan) -- no global atomics
    for (int i = tid; i < NBKT2; i += 256) resv[i] = hblk[(size_t)blockIdx.x * NBKT2 + i];
    __syncthreads();
    for (int i = tid; i < nloc; i += 256) {                  // coalesced run writes
        int c = sortedb[i];
        edgesA[Abase[c] + resv[c] + (i - start[c])] = sortedv[i];
    }
}

// one block per bucket: count -> 8-padded scan -> private-region scatter + pads,
// emits per-8-node-group [start,end) directly (rpS / wend8)
__global__ __launch_bounds__(256) void p2_kernel(const int* __restrict__ gsize,
                                                 const int* __restrict__ Abase,
                                                 const int* __restrict__ Bbase,
                                                 const int* __restrict__ edgesA,
                                                 int* __restrict__ edgesB,
                                                 int* __restrict__ rpS,
                                                 int* __restrict__ wend8) {
    __shared__ int cnt[256], off[256], pend[256], curx[256], tmp[4];
    int b = blockIdx.x, tid = threadIdx.x;
    int nb0 = b * 256;
    int nn = min(256, N_NODES - nb0);
    int ne = gsize[b];
    int abase = Abase[b], bbase = Bbase[b];
    cnt[tid] = 0;
    __syncthreads();
    for (int i = tid; i < ne; i += 256) atomicAdd(&cnt[edgesA[abase + i] >> 17], 1);
    __syncthreads();
    int c = cnt[tid];
    int c8 = (tid < nn) ? ((c + 7) & ~7) : 0;
    int o = blk_excl_scan_256(c8, tid, tmp);
    off[tid] = o; pend[tid] = o + c8; curx[tid] = bbase + o;
    __syncthreads();
    int gc = nn >> 3;
    if (tid < gc) {
        rpS[(nb0 >> 3) + tid] = bbase + off[tid * 8];
        wend8[(nb0 >> 3) + tid] = bbase + pend[tid * 8 + 7];
    }
    for (int i = tid; i < ne; i += 256) {
        int p = edgesA[abase + i];
        int dl = p >> 17;
        int pos = atomicAdd(&curx[dl], 1);
        edgesB[pos] = ((dl & 7) << 17) | (p & 0x1FFFF);   // wave-local row | src
    }
    __syncthreads();
    if (tid < nn) {   // sentinel pads
        int pe = bbase + pend[tid];
        int sent = ((tid & 7) << 17) | SENTSRC;
        for (int pos = curx[tid]; pos < pe; ++pos) edgesB[pos] = sent;
    }
}

__device__ __forceinline__ void flush_row(float* a, int row, int lane, float* agg_s) {
#pragma unroll
    for (int j = 0; j < 8; ++j) {
        a[j] += __shfl_xor(a[j], 8, 64);
        a[j] += __shfl_xor(a[j], 16, 64);
        a[j] += __shfl_xor(a[j], 32, 64);
    }
    if ((lane >> 3) == 0) {
#pragma unroll
        for (int j = 0; j < 8; ++j)
            agg_s[row * SA + (lane & 7) * 8 + j] = a[j];
    }
}

// ---------------- fused GraphConv layer (LAST fuses the pool) ----------------
template <bool LAST>
__global__ __launch_bounds__(BLOCK) void layer_kernel(
    const float* __restrict__ hin, const ushort8_t* __restrict__ hbf_in,
    float* __restrict__ hout, ushort4* __restrict__ hbf_out,
    const float* __restrict__ Wrel, const float* __restrict__ brel,
    const float* __restrict__ Wroot,
    const int* __restrict__ rpS, const int* __restrict__ wend8,
    const int* __restrict__ edges8,
    const int* __restrict__ batch, float* __restrict__ g) {
    __shared__ float agg_s[BN * SA];   // 16.6 KB
    const int tid = threadIdx.x;
    const int lane = tid & 63;
    const int wave = __builtin_amdgcn_readfirstlane(tid >> 6);
    const int grp8 = lane >> 3;
    const int gl8 = lane & 7;
    const int node0 = blockIdx.x * BN;
    const int nvalid = min(BN, N_NODES - node0);

#pragma unroll
    for (int r = 0; r < RPW; ++r) agg_s[(wave * RPW + r) * SA + lane] = 0.f;

    // Phase A: two 8-row segments per wave
#pragma unroll
    for (int seg = 0; seg < 2; ++seg) {
        const int gg = blockIdx.x * 8 + wave * 2 + seg;
        if (gg >= NGRP) break;
        const int eb = rpS[gg];
        const int nst = (wend8[gg] - eb) >> 3;
        if (nst <= 0) continue;
        const int rbase = wave * RPW + seg * 8;

        float a[8];
#pragma unroll
        for (int j = 0; j < 8; ++j) a[j] = 0.f;
        int cur = -1;

        const int lmax = nst * 8 - 1;
        const int l32 = lane & 31;
        int pv0 = edges8[eb + min(l32, lmax)];
        int pv1 = edges8[eb + min(32 + l32, lmax)];
        ushort8_t U0[4];
#pragma unroll
        for (int i = 0; i < 4; ++i) {
            int ps = __shfl(pv0, i * 8 + grp8, 64);
            U0[i] = hbf_in[(size_t)(ps & 0x1FFFF) * 8 + gl8];
        }
        for (int c = 0; c * 4 < nst; ++c) {
            int pvn = edges8[eb + min((c + 2) * 32 + l32, lmax)];
            ushort8_t Un[4];
#pragma unroll
            for (int i = 0; i < 4; ++i) {
                int ps = __shfl(pv1, i * 8 + grp8, 64);
                Un[i] = hbf_in[(size_t)(ps & 0x1FFFF) * 8 + gl8];
            }
#pragma unroll
            for (int i = 0; i < 4; ++i) {
                int t = c * 4 + i;
                if (t < nst) {
                    int lr = __builtin_amdgcn_readfirstlane(__shfl(pv0, i * 8, 64)) >> 17;
                    if (lr != cur) {
                        if (cur >= 0) flush_row(a, rbase + cur, lane, agg_s);
                        cur = lr;
#pragma unroll
                        for (int j = 0; j < 8; ++j) a[j] = 0.f;
                    }
#pragma unroll
                    for (int j = 0; j < 8; ++j) a[j] += b2f(U0[i][j]);
                }
            }
            pv0 = pv1; pv1 = pvn;
#pragma unroll
            for (int i = 0; i < 4; ++i) U0[i] = Un[i];
        }
        if (cur >= 0) flush_row(a, rbase + cur, lane, agg_s);
    }
    __syncthreads();

    // Phase B: node = lane, dims [wave*16, +16)
    const int d0 = wave * 16;
    float out[16];
#pragma unroll
    for (int j = 0; j < 16; ++j) out[j] = brel[d0 + j];
    const float* ar = &agg_s[lane * SA];
    const int nrow = min(node0 + lane, N_NODES - 1);
    const float4* xrow4 = reinterpret_cast<const float4*>(hin + (size_t)nrow * DIM);
    for (int kk = 0; kk < 16; ++kk) {
        float4 xq = xrow4[kk];
        float xa[4] = {xq.x, xq.y, xq.z, xq.w};
#pragma unroll
        for (int c = 0; c < 4; ++c) {
            int k = kk * 4 + c;
            float av = ar[k];
            float xv = xa[c];
            const float* wr = &Wrel[k * DIM + d0];
            const float* wo = &Wroot[k * DIM + d0];
#pragma unroll
            for (int j = 0; j < 16; ++j)
                out[j] = fmaf(av, wr[j], fmaf(xv, wo[j], out[j]));
        }
    }

    __syncthreads();
#pragma unroll
    for (int j = 0; j < 16; ++j) agg_s[lane * SA + d0 + j] = fmaxf(out[j], 0.f);
    __syncthreads();

    if (LAST) {
        // fused global_add_pool: wave 0, lane = dim; batch is sorted
        if (wave == 0) {
            float acc = 0.f;
            int cur = batch[node0];
            for (int nl = 0; nl < nvalid; ++nl) {
                int bv = batch[node0 + nl];          // wave-uniform scalar
                float v = agg_s[nl * SA + lane];
                if (bv != cur) {
                    unsafeAtomicAdd(&g[(size_t)cur * DIM + lane], acc);
                    acc = 0.f; cur = bv;
                }
                acc += v;
            }
            unsafeAtomicAdd(&g[(size_t)cur * DIM + lane], acc);
        }
    } else {
        // coalesced stores: fp32 h + bf16 gather copy (transpose via agg_s)
        for (int i = tid; i < nvalid * 16; i += BLOCK) {
            int nl = i >> 4, c4 = i & 15;
            const float* xp = &agg_s[nl * SA + c4 * 4];
            float4 v = make_float4(xp[0], xp[1], xp[2], xp[3]);
            reinterpret_cast<float4*>(hout)[(size_t)(node0 + nl) * 16 + c4] = v;
            ushort4 b;
            b.x = f2b(v.x); b.y = f2b(v.y); b.z = f2b(v.z); b.w = f2b(v.w);
            hbf_out[(size_t)(node0 + nl) * 16 + c4] = b;
        }
    }
}

// ---------------- classifier head ----------------
__global__ __launch_bounds__(256) void head_kernel(
    const float* __restrict__ g, const float* __restrict__ W1, const float* __restrict__ b1,
    const float* __restrict__ W2, const float* __restrict__ b2, float* __restrict__ y) {
    int gid = blockIdx.x * blockDim.x + threadIdx.x;
    if (gid >= N_GRAPHS) return;
    float t[DIM];
#pragma unroll
    for (int d = 0; d < DIM; ++d) t[d] = b1[d];
    const float4* gp = reinterpret_cast<const float4*>(g + (size_t)gid * DIM);
    for (int kk = 0; kk < DIM / 4; ++kk) {
        float4 gv = gp[kk];
        float ga[4] = {gv.x, gv.y, gv.z, gv.w};
#pragma unroll
        for (int c = 0; c < 4; ++c) {
            int k = 4 * kk + c;
            float v = ga[c];
#pragma unroll
            for (int d = 0; d < DIM; ++d) t[d] = fmaf(v, W1[k * DIM + d], t[d]);
        }
    }
#pragma unroll
    for (int d = 0; d < DIM; ++d) t[d] = fmaxf(t[d], 0.f);
    for (int o = 0; o < OUT_DIM; ++o) {
        float acc = b2[o];
#pragma unroll
        for (int d = 0; d < DIM; ++d) acc = fmaf(t[d], W2[d * OUT_DIM + o], acc);
        y[(size_t)gid * OUT_DIM + o] = acc;
    }
}

extern "C" void kernel_launch(void* const* d_in, const int* in_sizes, int n_in,
                              void* d_out, int out_size, void* d_ws, size_t ws_size,
                              hipStream_t stream) {
    const float* x     = (const float*)d_in[0];
    const int*   eidx  = (const int*)d_in[1];
    const int*   batch = (const int*)d_in[2];
    const float* Wrel  = (const float*)d_in[3];
    const float* brel  = (const float*)d_in[4];
    const float* Wroot = (const float*)d_in[5];
    const float* W1    = (const float*)d_in[6];
    const float* b1    = (const float*)d_in[7];
    const float* W2    = (const float*)d_in[8];
    const float* b2    = (const float*)d_in[9];
    float* y = (float*)d_out;

    char* ws = (char*)d_ws;
    const size_t HBYTES  = (size_t)N_NODES * DIM * sizeof(float);                // 25.6 MB
    const size_t BFBYTES = (size_t)(N_NODES + 1) * DIM * sizeof(unsigned short); // 12.8 MB + zero row
    size_t off = 0;
    float* hA = (float*)(ws + off); off += HBYTES;
    float* hB = (float*)(ws + off); off += HBYTES;
    ushort4* bf0 = (ushort4*)(ws + off); off += (BFBYTES + 255) / 256 * 256;
    ushort4* bf1 = (ushort4*)(ws + off); off += (BFBYTES + 255) / 256 * 256;
    int* rpS    = (int*)(ws + off); off += (size_t)NGRP * 4;
    int* wend8  = (int*)(ws + off); off += (size_t)NGRP * 4;
    int* gsize  = (int*)(ws + off); off += (size_t)NBKT2 * 4;
    int* Abase  = (int*)(ws + off); off += (size_t)NBKT2 * 4;
    int* Bbase  = (int*)(ws + off); off += (size_t)NBKT2 * 4;
    int* hblk   = (int*)(ws + off); off += (size_t)NBLK1 * NBKT2 * 4;  // 765 KB
    int* edgesA = (int*)(ws + off); off += (size_t)N_EDGES * 4;
    int* edgesB = (int*)(ws + off); off += (size_t)EPB * 4;
    float* g    = (float*)(ws + off); off += (size_t)N_GRAPHS * DIM * 4;

    const int* src = eidx;
    const int* dst = eidx + N_EDGES;

    // CSR build: prep -> parallel column scan -> tiny total scan -> p1 -> p2
    prep_kernel<<<NBLK1, 256, 0, stream>>>(dst, hblk, (const float4*)x, bf0, bf1, g);
    colscan_kernel<<<NBKT2, 256, 0, stream>>>(hblk, gsize);
    scanb2_kernel<<<1, 256, 0, stream>>>(gsize, Abase, Bbase);
    p1_kernel<<<NBLK1, 256, 0, stream>>>(src, dst, Abase, hblk, edgesA);
    p2_kernel<<<NBKT2, 256, 0, stream>>>(gsize, Abase, Bbase, edgesA, edgesB, rpS, wend8);

    // 4 GraphConv layers, ping-pong (fp32 + bf16 streams); last fuses pool
    layer_kernel<false><<<NB, BLOCK, 0, stream>>>(x, (const ushort8_t*)bf0, hA, bf1,
        Wrel + 0 * DIM * DIM, brel + 0 * DIM, Wroot + 0 * DIM * DIM,
        rpS, wend8, edgesB, batch, g);
    layer_kernel<false><<<NB, BLOCK, 0, stream>>>(hA, (const ushort8_t*)bf1, hB, bf0,
        Wrel + 1 * DIM * DIM, brel + 1 * DIM, Wroot + 1 * DIM * DIM,
        rpS, wend8, edgesB, batch, g);
    layer_kernel<false><<<NB, BLOCK, 0, stream>>>(hB, (const ushort8_t*)bf0, hA, bf1,
        Wrel + 2 * DIM * DIM, brel + 2 * DIM, Wroot + 2 * DIM * DIM,
        rpS, wend8, edgesB, batch, g);
    layer_kernel<true><<<NB, BLOCK, 0, stream>>>(hA, (const ushort8_t*)bf1, hB, bf0,
        Wrel + 3 * DIM * DIM, brel + 3 * DIM, Wroot + 3 * DIM * DIM,
        rpS, wend8, edgesB, batch, g);

    // head
    head_kernel<<<(N_GRAPHS + 255) / 256, 256, 0, stream>>>(g, W1, b1, W2, b2, y);
}

// Round 15
// 369.024 us; speedup vs baseline: 7.2375x; 1.0053x over previous
//
#include <hip/hip_runtime.h>

#define N_NODES 100000
#define N_EDGES 1000000
#define DIM 64
#define N_GRAPHS 1024
#define OUT_DIM 16
#define NLAYERS 4

#define BN 64        // nodes per block in layer kernel
#define NB 1563      // ceil(N_NODES/BN)
#define BLOCK 256    // 4 waves
#define NWAVES 4
#define RPW 16       // rows per wave = 2 padded 8-row groups
#define SA 65        // LDS row stride: 65%32==1 -> 2-way alias, free
#define NGRP 12500   // N_NODES/8 wave-groups

// ---- bucket sort params ----
#define NBKT2 391            // ceil(N_NODES/256) buckets of 256 dst nodes
#define BCH 2048             // edges per pass-1 block
#define NBLK1 489            // ceil(N_EDGES/BCH)
#define SLACK 1800           // per-bucket region slack: 256*7 pad + 8
#define EPB (N_EDGES + NBKT2 * SLACK)
#define SENTSRC N_NODES      // sentinel src -> zero bf16 row

typedef unsigned short ushort8_t __attribute__((ext_vector_type(8)));

__device__ __forceinline__ float b2f(unsigned short u) {
    union { unsigned int i; float f; } c;
    c.i = ((unsigned int)u) << 16;
    return c.f;
}
__device__ __forceinline__ unsigned short f2b(float f) {  // RNE
    union { float f; unsigned int i; } c;
    c.f = f;
    return (unsigned short)((c.i + 0x7FFFu + ((c.i >> 16) & 1u)) >> 16);
}

// block-wide exclusive scan of one int per thread (256 threads); tmp = 4+ ints LDS
__device__ __forceinline__ int blk_excl_scan_256(int v, int tid, int* tmp) {
    int lane = tid & 63, w = tid >> 6;
    int inc = v;
#pragma unroll
    for (int o = 1; o < 64; o <<= 1) { int u = __shfl_up(inc, o, 64); if (lane >= o) inc += u; }
    __syncthreads();              // protect tmp from any previous use
    if (lane == 63) tmp[w] = inc;
    __syncthreads();
    if (tid == 0) { int r = 0; for (int i = 0; i < 4; ++i) { int t2 = tmp[i]; tmp[i] = r; r += t2; } }
    __syncthreads();
    return inc - v + tmp[w];
}

// ---------------- prep: per-block histogram + tobf + zero g + sentinel rows ----------------
__global__ __launch_bounds__(256) void prep_kernel(const int* __restrict__ dst,
                                                   int* __restrict__ hblk,
                                                   const float4* __restrict__ x,
                                                   ushort4* __restrict__ bf0,
                                                   ushort4* __restrict__ bf1,
                                                   float* __restrict__ g) {
    __shared__ int h[NBKT2];
    int tid = threadIdx.x;
    for (int i = tid; i < NBKT2; i += 256) h[i] = 0;
    __syncthreads();
    int e0 = blockIdx.x * BCH;
    int nloc = min(BCH, N_EDGES - e0);
    for (int i = tid; i < nloc; i += 256) atomicAdd(&h[dst[e0 + i] >> 8], 1);  // LDS int: native

    // tobf (independent)
    const int n4 = N_NODES * (DIM / 4);
    for (int i = blockIdx.x * 256 + tid; i < n4; i += NBLK1 * 256) {
        float4 v = x[i];
        ushort4 b;
        b.x = f2b(v.x); b.y = f2b(v.y); b.z = f2b(v.z); b.w = f2b(v.w);
        bf0[i] = b;
    }
    // zero g (independent; pool is fused into last layer)
    const int g4 = N_GRAPHS * (DIM / 4);
    float4 z4 = make_float4(0.f, 0.f, 0.f, 0.f);
    for (int i = blockIdx.x * 256 + tid; i < g4; i += NBLK1 * 256)
        reinterpret_cast<float4*>(g)[i] = z4;
    // zero sentinel rows of both bf buffers
    if (blockIdx.x == 0 && tid < 32) {
        ushort4 z; z.x = 0; z.y = 0; z.z = 0; z.w = 0;
        if (tid < 16) bf0[(size_t)N_NODES * 16 + tid] = z;
        else          bf1[(size_t)N_NODES * 16 + (tid - 16)] = z;
    }
    __syncthreads();
    for (int i = tid; i < NBKT2; i += 256) hblk[(size_t)blockIdx.x * NBKT2 + i] = h[i];
}

// ---- column scan: one block per bucket, scan the 489 per-block counts ----
__global__ __launch_bounds__(256) void colscan_kernel(int* __restrict__ hblk,
                                                      int* __restrict__ gsize) {
    __shared__ int tmp[4];
    int c = blockIdx.x, t = threadIdx.x;
    int i0 = 2 * t, i1 = 2 * t + 1;
    int a = (i0 < NBLK1) ? hblk[(size_t)i0 * NBKT2 + c] : 0;
    int b = (i1 < NBLK1) ? hblk[(size_t)i1 * NBKT2 + c] : 0;
    int s = blk_excl_scan_256(a + b, t, tmp);
    if (i0 < NBLK1) hblk[(size_t)i0 * NBKT2 + c] = s;
    if (i1 < NBLK1) hblk[(size_t)i1 * NBKT2 + c] = s + a;
    if (t == 255) gsize[c] = s + a + b;   // column total
}

// tiny single block: scan 391 bucket totals -> Abase, Bbase
__global__ __launch_bounds__(256) void scanb2_kernel(const int* __restrict__ gsize,
                                                     int* __restrict__ Abase,
                                                     int* __restrict__ Bbase) {
    __shared__ int tmp[4];
    int t = threadIdx.x;
    int c0 = 2 * t, c1 = 2 * t + 1;
    int a = (c0 < NBKT2) ? gsize[c0] : 0;
    int b = (c1 < NBKT2) ? gsize[c1] : 0;
    int s = blk_excl_scan_256(a + b, t, tmp);
    if (c0 < NBKT2) Abase[c0] = s;
    if (c1 < NBKT2) Abase[c1] = s + a;
    int a2 = (c0 < NBKT2) ? a + SLACK : 0;
    int b2 = (c1 < NBKT2) ? b + SLACK : 0;
    int s2 = blk_excl_scan_256(a2 + b2, t, tmp);
    if (c0 < NBKT2) Bbase[c0] = s2;
    if (c1 < NBKT2) Bbase[c1] = s2 + a2;
}

__global__ __launch_bounds__(256) void p1_kernel(const int* __restrict__ src,
                                                 const int* __restrict__ dst,
                                                 const int* __restrict__ Abase,
                                                 const int* __restrict__ hblk,
                                                 int* __restrict__ edgesA) {
    __shared__ int h[NBKT2], start[NBKT2], curb[NBKT2], resv[NBKT2], tmp[4];
    __shared__ int sortedv[BCH];
    __shared__ unsigned short sortedb[BCH];
    int tid = threadIdx.x;
    int e0 = blockIdx.x * BCH;
    int nloc = min(BCH, N_EDGES - e0);
    for (int i = tid; i < NBKT2; i += 256) h[i] = 0;
    __syncthreads();
    int myc[8], myv[8];
#pragma unroll
    for (int k = 0; k < 8; ++k) {
        int i = k * 256 + tid;
        if (i < nloc) {
            int e = e0 + i;
            int d = dst[e];
            myc[k] = d >> 8;
            myv[k] = ((d & 255) << 17) | src[e];   // 8b local dst | 17b src
            atomicAdd(&h[myc[k]], 1);
        } else myc[k] = -1;
    }
    __syncthreads();
    {   // scan h -> start (2 elems/thread over 512 slots)
        int a = (2 * tid < NBKT2) ? h[2 * tid] : 0;
        int b = (2 * tid + 1 < NBKT2) ? h[2 * tid + 1] : 0;
        int s = blk_excl_scan_256(a + b, tid, tmp);
        if (2 * tid < NBKT2) start[2 * tid] = s;
        if (2 * tid + 1 < NBKT2) start[2 * tid + 1] = s + a;
    }
    __syncthreads();
    for (int i = tid; i < NBKT2; i += 256) curb[i] = start[i];
    __syncthreads();
#pragma unroll
    for (int k = 0; k < 8; ++k) if (myc[k] >= 0) {
        int r = atomicAdd(&curb[myc[k]], 1);
        sortedv[r] = myv[k];
        sortedb[r] = (unsigned short)myc[k];
    }
    __syncthreads();
    // reservation = precomputed block-prefix (colscan) -- no global atomics
    for (int i = tid; i < NBKT2; i += 256) resv[i] = hblk[(size_t)blockIdx.x * NBKT2 + i];
    __syncthreads();
    for (int i = tid; i < nloc; i += 256) {                  // coalesced run writes
        int c = sortedb[i];
        edgesA[Abase[c] + resv[c] + (i - start[c])] = sortedv[i];
    }
}

// one block per bucket: count -> 8-padded scan -> private-region scatter + pads,
// emits per-8-node-group [start,end) directly (rpS / wend8)
__global__ __launch_bounds__(256) void p2_kernel(const int* __restrict__ gsize,
                                                 const int* __restrict__ Abase,
                                                 const int* __restrict__ Bbase,
                                                 const int* __restrict__ edgesA,
                                                 int* __restrict__ edgesB,
                                                 int* __restrict__ rpS,
                                                 int* __restrict__ wend8) {
    __shared__ int cnt[256], off[256], pend[256], curx[256], tmp[4];
    int b = blockIdx.x, tid = threadIdx.x;
    int nb0 = b * 256;
    int nn = min(256, N_NODES - nb0);
    int ne = gsize[b];
    int abase = Abase[b], bbase = Bbase[b];
    cnt[tid] = 0;
    __syncthreads();
    for (int i = tid; i < ne; i += 256) atomicAdd(&cnt[edgesA[abase + i] >> 17], 1);
    __syncthreads();
    int c = cnt[tid];
    int c8 = (tid < nn) ? ((c + 7) & ~7) : 0;
    int o = blk_excl_scan_256(c8, tid, tmp);
    off[tid] = o; pend[tid] = o + c8; curx[tid] = bbase + o;
    __syncthreads();
    int gc = nn >> 3;
    if (tid < gc) {
        rpS[(nb0 >> 3) + tid] = bbase + off[tid * 8];
        wend8[(nb0 >> 3) + tid] = bbase + pend[tid * 8 + 7];
    }
    for (int i = tid; i < ne; i += 256) {
        int p = edgesA[abase + i];
        int dl = p >> 17;
        int pos = atomicAdd(&curx[dl], 1);
        edgesB[pos] = ((dl & 7) << 17) | (p & 0x1FFFF);   // wave-local row | src
    }
    __syncthreads();
    if (tid < nn) {   // sentinel pads
        int pe = bbase + pend[tid];
        int sent = ((tid & 7) << 17) | SENTSRC;
        for (int pos = curx[tid]; pos < pe; ++pos) edgesB[pos] = sent;
    }
}

__device__ __forceinline__ void flush_row(float* a, int row, int lane, float* agg_s) {
#pragma unroll
    for (int j = 0; j < 8; ++j) {
        a[j] += __shfl_xor(a[j], 8, 64);
        a[j] += __shfl_xor(a[j], 16, 64);
        a[j] += __shfl_xor(a[j], 32, 64);
    }
    if ((lane >> 3) == 0) {
#pragma unroll
        for (int j = 0; j < 8; ++j)
            agg_s[row * SA + (lane & 7) * 8 + j] = a[j];
    }
}

// ---------------- fused GraphConv layer: bf16-only h (fp32 compute) ----------
// Writes are free (LAST layer proved it: same 64us with 0.7 vs 37.5MB writes);
// time ~ FETCH. Dropping the fp32 h stream cuts the 25.6MB/layer Phase-B read
// to a 12.8MB bf16 read (partly L2-warm from gather) and the 38.4MB store to
// 12.8MB. All arithmetic stays fp32; only inter-layer storage is bf16.
template <bool LAST>
__global__ __launch_bounds__(BLOCK) void layer_kernel(
    const ushort8_t* __restrict__ hbf_in, ushort8_t* __restrict__ hbf_out,
    const float* __restrict__ Wrel, const float* __restrict__ brel,
    const float* __restrict__ Wroot,
    const int* __restrict__ rpS, const int* __restrict__ wend8,
    const int* __restrict__ edges8,
    const int* __restrict__ batch, float* __restrict__ g) {
    __shared__ float agg_s[BN * SA];   // 16.6 KB
    const int tid = threadIdx.x;
    const int lane = tid & 63;
    const int wave = __builtin_amdgcn_readfirstlane(tid >> 6);
    const int grp8 = lane >> 3;
    const int gl8 = lane & 7;
    const int node0 = blockIdx.x * BN;
    const int nvalid = min(BN, N_NODES - node0);

#pragma unroll
    for (int r = 0; r < RPW; ++r) agg_s[(wave * RPW + r) * SA + lane] = 0.f;

    // Phase A: two 8-row segments per wave
#pragma unroll
    for (int seg = 0; seg < 2; ++seg) {
        const int gg = blockIdx.x * 8 + wave * 2 + seg;
        if (gg >= NGRP) break;
        const int eb = rpS[gg];
        const int nst = (wend8[gg] - eb) >> 3;
        if (nst <= 0) continue;
        const int rbase = wave * RPW + seg * 8;

        float a[8];
#pragma unroll
        for (int j = 0; j < 8; ++j) a[j] = 0.f;
        int cur = -1;

        const int lmax = nst * 8 - 1;
        const int l32 = lane & 31;
        int pv0 = edges8[eb + min(l32, lmax)];
        int pv1 = edges8[eb + min(32 + l32, lmax)];
        ushort8_t U0[4];
#pragma unroll
        for (int i = 0; i < 4; ++i) {
            int ps = __shfl(pv0, i * 8 + grp8, 64);
            U0[i] = hbf_in[(size_t)(ps & 0x1FFFF) * 8 + gl8];
        }
        for (int c = 0; c * 4 < nst; ++c) {
            int pvn = edges8[eb + min((c + 2) * 32 + l32, lmax)];
            ushort8_t Un[4];
#pragma unroll
            for (int i = 0; i < 4; ++i) {
                int ps = __shfl(pv1, i * 8 + grp8, 64);
                Un[i] = hbf_in[(size_t)(ps & 0x1FFFF) * 8 + gl8];
            }
#pragma unroll
            for (int i = 0; i < 4; ++i) {
                int t = c * 4 + i;
                if (t < nst) {
                    int lr = __builtin_amdgcn_readfirstlane(__shfl(pv0, i * 8, 64)) >> 17;
                    if (lr != cur) {
                        if (cur >= 0) flush_row(a, rbase + cur, lane, agg_s);
                        cur = lr;
#pragma unroll
                        for (int j = 0; j < 8; ++j) a[j] = 0.f;
                    }
#pragma unroll
                    for (int j = 0; j < 8; ++j) a[j] += b2f(U0[i][j]);
                }
            }
            pv0 = pv1; pv1 = pvn;
#pragma unroll
            for (int i = 0; i < 4; ++i) U0[i] = Un[i];
        }
        if (cur >= 0) flush_row(a, rbase + cur, lane, agg_s);
    }
    __syncthreads();

    // Phase B: node = lane, dims [wave*16, +16); own row read from bf16
    const int d0 = wave * 16;
    float out[16];
#pragma unroll
    for (int j = 0; j < 16; ++j) out[j] = brel[d0 + j];
    const float* ar = &agg_s[lane * SA];
    const int nrow = min(node0 + lane, N_NODES - 1);
    const ushort8_t* xrow8 = &hbf_in[(size_t)nrow * 8];
    for (int kk = 0; kk < 8; ++kk) {
        ushort8_t xq = xrow8[kk];   // own row: 8KB/block, L2/L1-warm
#pragma unroll
        for (int c = 0; c < 8; ++c) {
            int k = kk * 8 + c;
            float av = ar[k];
            float xv = b2f(xq[c]);
            const float* wr = &Wrel[k * DIM + d0];
            const float* wo = &Wroot[k * DIM + d0];
#pragma unroll
            for (int j = 0; j < 16; ++j)
                out[j] = fmaf(av, wr[j], fmaf(xv, wo[j], out[j]));
        }
    }

    __syncthreads();
#pragma unroll
    for (int j = 0; j < 16; ++j) agg_s[lane * SA + d0 + j] = fmaxf(out[j], 0.f);
    __syncthreads();

    if (LAST) {
        // fused global_add_pool: wave 0, lane = dim; batch is sorted
        if (wave == 0) {
            float acc = 0.f;
            int cur = batch[node0];
            for (int nl = 0; nl < nvalid; ++nl) {
                int bv = batch[node0 + nl];          // wave-uniform scalar
                float v = agg_s[nl * SA + lane];
                if (bv != cur) {
                    unsafeAtomicAdd(&g[(size_t)cur * DIM + lane], acc);
                    acc = 0.f; cur = bv;
                }
                acc += v;
            }
            unsafeAtomicAdd(&g[(size_t)cur * DIM + lane], acc);
        }
    } else {
        // coalesced bf16 store only (transpose via agg_s)
        for (int i = tid; i < nvalid * 8; i += BLOCK) {
            int nl = i >> 3, c8 = i & 7;
            const float* xp = &agg_s[nl * SA + c8 * 8];
            ushort8_t b;
#pragma unroll
            for (int j = 0; j < 8; ++j) b[j] = f2b(xp[j]);
            hbf_out[(size_t)(node0 + nl) * 8 + c8] = b;
        }
    }
}

// ---------------- classifier head ----------------
__global__ __launch_bounds__(256) void head_kernel(
    const float* __restrict__ g, const float* __restrict__ W1, const float* __restrict__ b1,
    const float* __restrict__ W2, const float* __restrict__ b2, float* __restrict__ y) {
    int gid = blockIdx.x * blockDim.x + threadIdx.x;
    if (gid >= N_GRAPHS) return;
    float t[DIM];
#pragma unroll
    for (int d = 0; d < DIM; ++d) t[d] = b1[d];
    const float4* gp = reinterpret_cast<const float4*>(g + (size_t)gid * DIM);
    for (int kk = 0; kk < DIM / 4; ++kk) {
        float4 gv = gp[kk];
        float ga[4] = {gv.x, gv.y, gv.z, gv.w};
#pragma unroll
        for (int c = 0; c < 4; ++c) {
            int k = 4 * kk + c;
            float v = ga[c];
#pragma unroll
            for (int d = 0; d < DIM; ++d) t[d] = fmaf(v, W1[k * DIM + d], t[d]);
        }
    }
#pragma unroll
    for (int d = 0; d < DIM; ++d) t[d] = fmaxf(t[d], 0.f);
    for (int o = 0; o < OUT_DIM; ++o) {
        float acc = b2[o];
#pragma unroll
        for (int d = 0; d < DIM; ++d) acc = fmaf(t[d], W2[d * OUT_DIM + o], acc);
        y[(size_t)gid * OUT_DIM + o] = acc;
    }
}

extern "C" void kernel_launch(void* const* d_in, const int* in_sizes, int n_in,
                              void* d_out, int out_size, void* d_ws, size_t ws_size,
                              hipStream_t stream) {
    const float* x     = (const float*)d_in[0];
    const int*   eidx  = (const int*)d_in[1];
    const int*   batch = (const int*)d_in[2];
    const float* Wrel  = (const float*)d_in[3];
    const float* brel  = (const float*)d_in[4];
    const float* Wroot = (const float*)d_in[5];
    const float* W1    = (const float*)d_in[6];
    const float* b1    = (const float*)d_in[7];
    const float* W2    = (const float*)d_in[8];
    const float* b2    = (const float*)d_in[9];
    float* y = (float*)d_out;

    char* ws = (char*)d_ws;
    const size_t BFBYTES = (size_t)(N_NODES + 1) * DIM * sizeof(unsigned short); // 12.8 MB + zero row
    size_t off = 0;
    ushort4* bf0 = (ushort4*)(ws + off); off += (BFBYTES + 255) / 256 * 256;
    ushort4* bf1 = (ushort4*)(ws + off); off += (BFBYTES + 255) / 256 * 256;
    int* rpS    = (int*)(ws + off); off += (size_t)NGRP * 4;
    int* wend8  = (int*)(ws + off); off += (size_t)NGRP * 4;
    int* gsize  = (int*)(ws + off); off += (size_t)NBKT2 * 4;
    int* Abase  = (int*)(ws + off); off += (size_t)NBKT2 * 4;
    int* Bbase  = (int*)(ws + off); off += (size_t)NBKT2 * 4;
    int* hblk   = (int*)(ws + off); off += (size_t)NBLK1 * NBKT2 * 4;  // 765 KB
    int* edgesA = (int*)(ws + off); off += (size_t)N_EDGES * 4;
    int* edgesB = (int*)(ws + off); off += (size_t)EPB * 4;
    float* g    = (float*)(ws + off); off += (size_t)N_GRAPHS * DIM * 4;

    const int* src = eidx;
    const int* dst = eidx + N_EDGES;

    // CSR build: prep -> parallel column scan -> tiny total scan -> p1 -> p2
    prep_kernel<<<NBLK1, 256, 0, stream>>>(dst, hblk, (const float4*)x, bf0, bf1, g);
    colscan_kernel<<<NBKT2, 256, 0, stream>>>(hblk, gsize);
    scanb2_kernel<<<1, 256, 0, stream>>>(gsize, Abase, Bbase);
    p1_kernel<<<NBLK1, 256, 0, stream>>>(src, dst, Abase, hblk, edgesA);
    p2_kernel<<<NBKT2, 256, 0, stream>>>(gsize, Abase, Bbase, edgesA, edgesB, rpS, wend8);

    // 4 GraphConv layers, bf16 ping-pong; last fuses pool
    layer_kernel<false><<<NB, BLOCK, 0, stream>>>((const ushort8_t*)bf0, (ushort8_t*)bf1,
        Wrel + 0 * DIM * DIM, brel + 0 * DIM, Wroot + 0 * DIM * DIM,
        rpS, wend8, edgesB, batch, g);
    layer_kernel<false><<<NB, BLOCK, 0, stream>>>((const ushort8_t*)bf1, (ushort8_t*)bf0,
        Wrel + 1 * DIM * DIM, brel + 1 * DIM, Wroot + 1 * DIM * DIM,
        rpS, wend8, edgesB, batch, g);
    layer_kernel<false><<<NB, BLOCK, 0, stream>>>((const ushort8_t*)bf0, (ushort8_t*)bf1,
        Wrel + 2 * DIM * DIM, brel + 2 * DIM, Wroot + 2 * DIM * DIM,
        rpS, wend8, edgesB, batch, g);
    layer_kernel<true><<<NB, BLOCK, 0, stream>>>((const ushort8_t*)bf1, (ushort8_t*)bf0,
        Wrel + 3 * DIM * DIM, brel + 3 * DIM, Wroot + 3 * DIM * DIM,
        rpS, wend8, edgesB, batch, g);

    // head
    head_kernel<<<(N_GRAPHS + 255) / 256, 256, 0, stream>>>(g, W1, b1, W2, b2, y);
}